// Round 2
// baseline (3969.889 us; speedup 1.0000x reference)
//
#include <hip/hip_runtime.h>

#define N_NODES 50000
#define N_EDGES 1600000
#define NFEAT   512
#define HIDDEN  128
#define NCLASS  40

// ---------------------------------------------------------------------------
// JAX threefry2x32, 20 rounds, key = jax.random.key(42) -> (k1,k2) = (0,42).
// Partitionable path (jax >= 0.4.36 default): for 32-bit draws,
// bits[i] = o0 ^ o1 of threefry((0,42), (i>>32, i&0xffffffff))   [prng.py:
// _threefry_random_bits_partitionable returns bits1 ^ bits2 for width<=32].
// bernoulli(p=0.5): keep iff uniform<0.5 iff (bits>>31)==0.
// ---------------------------------------------------------------------------
__device__ __forceinline__ unsigned rotl32(unsigned x, int n) {
  return (x << n) | (x >> (32 - n));
}

__device__ __forceinline__ void threefry_0_42(unsigned x0, unsigned x1,
                                              unsigned& o0, unsigned& o1) {
  const unsigned ks0 = 0u, ks1 = 42u, ks2 = 0x1BD11BDAu ^ 42u;
  x0 += ks0; x1 += ks1;
#define TFR(r) { x0 += x1; x1 = rotl32(x1, (r)); x1 ^= x0; }
  TFR(13) TFR(15) TFR(26) TFR(6)
  x0 += ks1; x1 += ks2 + 1u;
  TFR(17) TFR(29) TFR(16) TFR(24)
  x0 += ks2; x1 += ks0 + 2u;
  TFR(13) TFR(15) TFR(26) TFR(6)
  x0 += ks0; x1 += ks1 + 3u;
  TFR(17) TFR(29) TFR(16) TFR(24)
  x0 += ks1; x1 += ks2 + 4u;
  TFR(13) TFR(15) TFR(26) TFR(6)
  x0 += ks2; x1 += ks0 + 5u;
#undef TFR
  o0 = x0; o1 = x1;
}

__device__ __forceinline__ void fma4(float4& a, float s, const float4 b) {
  a.x += s * b.x; a.y += s * b.y; a.z += s * b.z; a.w += s * b.w;
}

// ---------------------------------------------------------------------------
// GEMM1: support[50000,128] = x[50000,512] @ W1[512,128], fp32.
// Tile: 128 nodes x 128 feats, TK=32. 256 threads, each owns 8x8 outputs
// split as nodes {ty*4..+3, +64}, feats {tx*4..+3, +64} (<=2-way LDS alias).
// ---------------------------------------------------------------------------
__global__ __launch_bounds__(256) void gemm1_kernel(
    const float* __restrict__ x, const float* __restrict__ W1,
    float* __restrict__ support) {
  __shared__ float As[32][128];  // [k][node] (transposed on stage-in)
  __shared__ float Bs[32][128];  // [k][feat]
  const int t = threadIdx.x;
  const int tx = t & 15, ty = t >> 4;
  const int node_base = blockIdx.x * 128;

  float4 acc[2][4][2];  // [node-half][node-sub][feat-half]
#pragma unroll
  for (int a = 0; a < 2; a++)
#pragma unroll
    for (int b = 0; b < 4; b++)
#pragma unroll
      for (int c = 0; c < 2; c++) acc[a][b][c] = make_float4(0.f, 0.f, 0.f, 0.f);

  for (int k0 = 0; k0 < NFEAT; k0 += 32) {
    // stage A: 128 nodes x 32 k, transpose into As[k][node]
#pragma unroll
    for (int i = 0; i < 4; i++) {
      int nloc = (t >> 3) + i * 32;
      int n = node_base + nloc;
      if (n >= N_NODES) n = N_NODES - 1;  // clamp; result discarded at store
      int kl = (t & 7) * 4;
      float4 v = *(const float4*)&x[(size_t)n * NFEAT + k0 + kl];
      As[kl + 0][nloc] = v.x; As[kl + 1][nloc] = v.y;
      As[kl + 2][nloc] = v.z; As[kl + 3][nloc] = v.w;
    }
    // stage B: 32 k x 128 f, direct copy
#pragma unroll
    for (int i = 0; i < 4; i++) {
      int l = i * 1024 + t * 4;
      int r = l >> 7, c = l & 127;
      *(float4*)&Bs[r][c] = *(const float4*)&W1[(k0 + r) * HIDDEN + c];
    }
    __syncthreads();
#pragma unroll 8
    for (int kk = 0; kk < 32; kk++) {
      float4 a0 = *(const float4*)&As[kk][ty * 4];
      float4 a1 = *(const float4*)&As[kk][ty * 4 + 64];
      float4 b0 = *(const float4*)&Bs[kk][tx * 4];
      float4 b1 = *(const float4*)&Bs[kk][tx * 4 + 64];
      fma4(acc[0][0][0], a0.x, b0); fma4(acc[0][1][0], a0.y, b0);
      fma4(acc[0][2][0], a0.z, b0); fma4(acc[0][3][0], a0.w, b0);
      fma4(acc[0][0][1], a0.x, b1); fma4(acc[0][1][1], a0.y, b1);
      fma4(acc[0][2][1], a0.z, b1); fma4(acc[0][3][1], a0.w, b1);
      fma4(acc[1][0][0], a1.x, b0); fma4(acc[1][1][0], a1.y, b0);
      fma4(acc[1][2][0], a1.z, b0); fma4(acc[1][3][0], a1.w, b0);
      fma4(acc[1][0][1], a1.x, b1); fma4(acc[1][1][1], a1.y, b1);
      fma4(acc[1][2][1], a1.z, b1); fma4(acc[1][3][1], a1.w, b1);
    }
    __syncthreads();
  }
#pragma unroll
  for (int nh = 0; nh < 2; nh++)
#pragma unroll
    for (int ni = 0; ni < 4; ni++) {
      int n = node_base + nh * 64 + ty * 4 + ni;
      if (n < N_NODES) {
        *(float4*)&support[(size_t)n * HIDDEN + tx * 4]      = acc[nh][ni][0];
        *(float4*)&support[(size_t)n * HIDDEN + tx * 4 + 64] = acc[nh][ni][1];
      }
    }
}

// ---------------------------------------------------------------------------
// SpMM1: h[row[e],:] += vals[e] * support[col[e],:]  (F=128, atomics)
// One thread per (edge, float4-chunk): 32 chunks/edge.
// ---------------------------------------------------------------------------
__global__ __launch_bounds__(256) void spmm1_kernel(
    const int* __restrict__ erow, const int* __restrict__ ecol,
    const float* __restrict__ evals, const float* __restrict__ support,
    float* __restrict__ h) {
  unsigned id = blockIdx.x * 256 + threadIdx.x;  // < 51.2M
  unsigned e = id >> 5;
  unsigned c = id & 31;
  int r = erow[e], cl = ecol[e];
  float v = evals[e];
  float4 s = *(const float4*)&support[(size_t)cl * HIDDEN + c * 4];
  float* dst = &h[(size_t)r * HIDDEN + c * 4];
  unsafeAtomicAdd(dst + 0, v * s.x);
  unsafeAtomicAdd(dst + 1, v * s.y);
  unsafeAtomicAdd(dst + 2, v * s.z);
  unsafeAtomicAdd(dst + 3, v * s.w);
}

// ---------------------------------------------------------------------------
// h = dropout(relu(h + b1))  with exact JAX threefry mask, flat idx i.
// ---------------------------------------------------------------------------
__global__ __launch_bounds__(256) void bias_relu_dropout_kernel(
    float* __restrict__ h, const float* __restrict__ b1) {
  unsigned i = blockIdx.x * 256 + threadIdx.x;  // exactly 6.4M threads
  unsigned o0, o1;
  threefry_0_42(0u, i, o0, o1);
  unsigned bits = o0 ^ o1;  // partitionable path: bits1 ^ bits2 for 32-bit
  float v = h[i] + b1[i & (HIDDEN - 1)];
  v = fmaxf(v, 0.f);
  h[i] = (bits >> 31) ? 0.f : 2.f * v;
}

// ---------------------------------------------------------------------------
// GEMM2: h2[50000,40] = h[50000,128] @ W2[128,40].
// 64 nodes/block; h tile + W2^T in LDS (stride 132 to break bank conflicts).
// Thread (nloc = t>>2, fb = t&3) computes feats fb+4j, j<10.
// ---------------------------------------------------------------------------
__global__ __launch_bounds__(256) void gemm2_kernel(
    const float* __restrict__ h, const float* __restrict__ W2,
    float* __restrict__ h2) {
  __shared__ float Hs[64][132];
  __shared__ float Ws[40][132];
  const int t = threadIdx.x;
  const int node_base = blockIdx.x * 64;
#pragma unroll
  for (int i = 0; i < 8; i++) {
    int l = t + i * 256;  // float4 index over 2048
    int nloc = l >> 5, kq = l & 31;
    int n = node_base + nloc;
    if (n >= N_NODES) n = N_NODES - 1;
    float4 v = *(const float4*)&h[(size_t)n * HIDDEN + kq * 4];
    *(float4*)&Hs[nloc][kq * 4] = v;
  }
#pragma unroll
  for (int i = 0; i < 20; i++) {
    int l = t + i * 256;  // 0..5119
    int k = l / NCLASS, f = l % NCLASS;
    Ws[f][k] = W2[l];
  }
  __syncthreads();
  const int nloc = t >> 2;
  const int fb = t & 3;
  const int n = node_base + nloc;
  float acc[10];
#pragma unroll
  for (int j = 0; j < 10; j++) acc[j] = 0.f;
  for (int k = 0; k < HIDDEN; k += 4) {
    float4 a = *(const float4*)&Hs[nloc][k];
#pragma unroll
    for (int j = 0; j < 10; j++) {
      float4 w = *(const float4*)&Ws[fb + 4 * j][k];
      acc[j] += a.x * w.x + a.y * w.y + a.z * w.z + a.w * w.w;
    }
  }
  if (n < N_NODES) {
#pragma unroll
    for (int j = 0; j < 10; j++) h2[(size_t)n * NCLASS + fb + 4 * j] = acc[j];
  }
}

// ---------------------------------------------------------------------------
// SpMM2: out[row[e],:] += vals[e] * h2[col[e],:]  (F=40, atomics)
// One thread per (edge, float4-chunk): 10 chunks/edge. Grid is exact.
// ---------------------------------------------------------------------------
__global__ __launch_bounds__(256) void spmm2_kernel(
    const int* __restrict__ erow, const int* __restrict__ ecol,
    const float* __restrict__ evals, const float* __restrict__ h2,
    float* __restrict__ out) {
  unsigned id = blockIdx.x * 256 + threadIdx.x;  // < 16M exactly
  unsigned e = id / 10;
  unsigned c = id % 10;
  int r = erow[e], cl = ecol[e];
  float v = evals[e];
  float4 s = *(const float4*)&h2[(size_t)cl * NCLASS + c * 4];
  float* dst = &out[(size_t)r * NCLASS + c * 4];
  unsafeAtomicAdd(dst + 0, v * s.x);
  unsafeAtomicAdd(dst + 1, v * s.y);
  unsafeAtomicAdd(dst + 2, v * s.z);
  unsafeAtomicAdd(dst + 3, v * s.w);
}

__global__ __launch_bounds__(256) void bias_relu_out_kernel(
    float* __restrict__ out, const float* __restrict__ b2) {
  unsigned i = blockIdx.x * 256 + threadIdx.x;
  if (i >= (unsigned)(N_NODES * NCLASS)) return;
  float v = out[i] + b2[i % NCLASS];
  out[i] = fmaxf(v, 0.f);
}

extern "C" void kernel_launch(void* const* d_in, const int* in_sizes, int n_in,
                              void* d_out, int out_size, void* d_ws,
                              size_t ws_size, hipStream_t stream) {
  const float* x     = (const float*)d_in[0];
  const int*   erow  = (const int*)d_in[1];
  const int*   ecol  = (const int*)d_in[2];
  const float* evals = (const float*)d_in[3];
  const float* W1    = (const float*)d_in[4];
  const float* b1    = (const float*)d_in[5];
  const float* W2    = (const float*)d_in[6];
  const float* b2    = (const float*)d_in[7];
  float* out = (float*)d_out;

  // workspace layout (floats): support[6.4M] | h[6.4M] | h2[2M]  = 59.2 MB
  float* support = (float*)d_ws;
  float* h  = support + (size_t)N_NODES * HIDDEN;
  float* h2 = h + (size_t)N_NODES * HIDDEN;

  // zero the atomic accumulators (ws/out are poisoned before every launch)
  hipMemsetAsync(h, 0, (size_t)N_NODES * HIDDEN * sizeof(float), stream);
  hipMemsetAsync(out, 0, (size_t)N_NODES * NCLASS * sizeof(float), stream);

  gemm1_kernel<<<(N_NODES + 127) / 128, 256, 0, stream>>>(x, W1, support);
  spmm1_kernel<<<(N_EDGES * 32) / 256, 256, 0, stream>>>(erow, ecol, evals,
                                                         support, h);
  bias_relu_dropout_kernel<<<(N_NODES * HIDDEN) / 256, 256, 0, stream>>>(h, b1);
  gemm2_kernel<<<(N_NODES + 63) / 64, 256, 0, stream>>>(h, W2, h2);
  spmm2_kernel<<<(N_EDGES * 10) / 256, 256, 0, stream>>>(erow, ecol, evals, h2,
                                                         out);
  bias_relu_out_kernel<<<(N_NODES * NCLASS + 255) / 256, 256, 0, stream>>>(out,
                                                                           b2);
}

// Round 3
// 771.587 us; speedup vs baseline: 5.1451x; 5.1451x over previous
//
#include <hip/hip_runtime.h>

#define N_NODES 50000
#define N_EDGES 1600000
#define NFEAT   512
#define HIDDEN  128
#define NCLASS  40

// ---------------------------------------------------------------------------
// JAX threefry2x32, 20 rounds, key = jax.random.key(42) -> (k1,k2) = (0,42).
// Partitionable path: bits[i] = o0 ^ o1 of threefry((0,42), (0, i)).
// bernoulli(p=0.5): keep iff (bits>>31)==0.   (verified round 2: absmax 0.25)
// ---------------------------------------------------------------------------
__device__ __forceinline__ unsigned rotl32(unsigned x, int n) {
  return (x << n) | (x >> (32 - n));
}

__device__ __forceinline__ unsigned threefry_bits(unsigned x1) {
  unsigned x0 = 0u;
  const unsigned ks0 = 0u, ks1 = 42u, ks2 = 0x1BD11BDAu ^ 42u;
  x0 += ks0; x1 += ks1;
#define TFR(r) { x0 += x1; x1 = rotl32(x1, (r)); x1 ^= x0; }
  TFR(13) TFR(15) TFR(26) TFR(6)
  x0 += ks1; x1 += ks2 + 1u;
  TFR(17) TFR(29) TFR(16) TFR(24)
  x0 += ks2; x1 += ks0 + 2u;
  TFR(13) TFR(15) TFR(26) TFR(6)
  x0 += ks0; x1 += ks1 + 3u;
  TFR(17) TFR(29) TFR(16) TFR(24)
  x0 += ks1; x1 += ks2 + 4u;
  TFR(13) TFR(15) TFR(26) TFR(6)
  x0 += ks2; x1 += ks0 + 5u;
#undef TFR
  return x0 ^ x1;  // bits1 ^ bits2 (partitionable 32-bit draw)
}

__device__ __forceinline__ void fma4(float4& a, float s, const float4 b) {
  a.x += s * b.x; a.y += s * b.y; a.z += s * b.z; a.w += s * b.w;
}

// ---------------------------------------------------------------------------
// CSR build: histogram -> single-block scan -> scatter.
// ---------------------------------------------------------------------------
__global__ __launch_bounds__(256) void hist_kernel(
    const int* __restrict__ erow, int* __restrict__ deg) {
  unsigned e = blockIdx.x * 256 + threadIdx.x;  // grid exact: 1.6M
  atomicAdd(&deg[erow[e]], 1);
}

// one workgroup, 1024 threads: exclusive scan of deg[50000] -> rowptr, cursor
__global__ __launch_bounds__(1024) void scan_kernel(
    const int* __restrict__ deg, int* __restrict__ rowptr,
    int* __restrict__ cursor) {
  __shared__ int s[1024];
  const int t = threadIdx.x;
  const int chunk = (N_NODES + 1023) / 1024;  // 49
  const int lo = t * chunk;
  const int hi = min(lo + chunk, N_NODES);
  int sum = 0;
  for (int i = lo; i < hi; i++) sum += deg[i];
  s[t] = sum;
  __syncthreads();
  // Hillis-Steele inclusive scan over 1024
  for (int off = 1; off < 1024; off <<= 1) {
    int v = (t >= off) ? s[t - off] : 0;
    __syncthreads();
    s[t] += v;
    __syncthreads();
  }
  int run = (t == 0) ? 0 : s[t - 1];
  for (int i = lo; i < hi; i++) {
    int d = deg[i];
    rowptr[i] = run;
    cursor[i] = run;
    run += d;
  }
  if (t == 1023) rowptr[N_NODES] = N_EDGES;
}

__global__ __launch_bounds__(256) void scatter_kernel(
    const int* __restrict__ erow, const int* __restrict__ ecol,
    const float* __restrict__ evals, int* __restrict__ cursor,
    int2* __restrict__ csr) {
  unsigned e = blockIdx.x * 256 + threadIdx.x;  // grid exact
  int r = erow[e];
  int p = atomicAdd(&cursor[r], 1);
  csr[p] = make_int2(ecol[e], __float_as_int(evals[e]));
}

// ---------------------------------------------------------------------------
// GEMM1: support[50000,128] = x[50000,512] @ W1[512,128], fp32.
// ---------------------------------------------------------------------------
__global__ __launch_bounds__(256) void gemm1_kernel(
    const float* __restrict__ x, const float* __restrict__ W1,
    float* __restrict__ support) {
  __shared__ float As[32][128];  // [k][node]
  __shared__ float Bs[32][128];  // [k][feat]
  const int t = threadIdx.x;
  const int tx = t & 15, ty = t >> 4;
  const int node_base = blockIdx.x * 128;

  float4 acc[2][4][2];
#pragma unroll
  for (int a = 0; a < 2; a++)
#pragma unroll
    for (int b = 0; b < 4; b++)
#pragma unroll
      for (int c = 0; c < 2; c++) acc[a][b][c] = make_float4(0.f, 0.f, 0.f, 0.f);

  for (int k0 = 0; k0 < NFEAT; k0 += 32) {
#pragma unroll
    for (int i = 0; i < 4; i++) {
      int nloc = (t >> 3) + i * 32;
      int n = node_base + nloc;
      if (n >= N_NODES) n = N_NODES - 1;
      int kl = (t & 7) * 4;
      float4 v = *(const float4*)&x[(size_t)n * NFEAT + k0 + kl];
      As[kl + 0][nloc] = v.x; As[kl + 1][nloc] = v.y;
      As[kl + 2][nloc] = v.z; As[kl + 3][nloc] = v.w;
    }
#pragma unroll
    for (int i = 0; i < 4; i++) {
      int l = i * 1024 + t * 4;
      int r = l >> 7, c = l & 127;
      *(float4*)&Bs[r][c] = *(const float4*)&W1[(k0 + r) * HIDDEN + c];
    }
    __syncthreads();
#pragma unroll 8
    for (int kk = 0; kk < 32; kk++) {
      float4 a0 = *(const float4*)&As[kk][ty * 4];
      float4 a1 = *(const float4*)&As[kk][ty * 4 + 64];
      float4 b0 = *(const float4*)&Bs[kk][tx * 4];
      float4 b1 = *(const float4*)&Bs[kk][tx * 4 + 64];
      fma4(acc[0][0][0], a0.x, b0); fma4(acc[0][1][0], a0.y, b0);
      fma4(acc[0][2][0], a0.z, b0); fma4(acc[0][3][0], a0.w, b0);
      fma4(acc[0][0][1], a0.x, b1); fma4(acc[0][1][1], a0.y, b1);
      fma4(acc[0][2][1], a0.z, b1); fma4(acc[0][3][1], a0.w, b1);
      fma4(acc[1][0][0], a1.x, b0); fma4(acc[1][1][0], a1.y, b0);
      fma4(acc[1][2][0], a1.z, b0); fma4(acc[1][3][0], a1.w, b0);
      fma4(acc[1][0][1], a1.x, b1); fma4(acc[1][1][1], a1.y, b1);
      fma4(acc[1][2][1], a1.z, b1); fma4(acc[1][3][1], a1.w, b1);
    }
    __syncthreads();
  }
#pragma unroll
  for (int nh = 0; nh < 2; nh++)
#pragma unroll
    for (int ni = 0; ni < 4; ni++) {
      int n = node_base + nh * 64 + ty * 4 + ni;
      if (n < N_NODES) {
        *(float4*)&support[(size_t)n * HIDDEN + tx * 4]      = acc[nh][ni][0];
        *(float4*)&support[(size_t)n * HIDDEN + tx * 4 + 64] = acc[nh][ni][1];
      }
    }
}

// ---------------------------------------------------------------------------
// SpMM1 fused: wave per row. lane l accumulates cols (2l, 2l+1) of
// h[row] = dropout(relu(sum_e val*support[col] + b1)).
// ---------------------------------------------------------------------------
__global__ __launch_bounds__(256) void spmm1_fused(
    const int2* __restrict__ csr, const int* __restrict__ rowptr,
    const float* __restrict__ support, const float* __restrict__ b1,
    float* __restrict__ h) {
  const int row = blockIdx.x * 4 + (threadIdx.x >> 6);  // grid exact: 12500
  const int lane = threadIdx.x & 63;
  const int beg = rowptr[row], end = rowptr[row + 1];
  float ax = 0.f, ay = 0.f;
  int j = beg;
  for (; j + 1 < end; j += 2) {  // 2-edge unroll for MLP
    int2 c0 = csr[j];
    int2 c1 = csr[j + 1];
    float2 s0 = *(const float2*)&support[(size_t)c0.x * HIDDEN + lane * 2];
    float2 s1 = *(const float2*)&support[(size_t)c1.x * HIDDEN + lane * 2];
    float v0 = __int_as_float(c0.y), v1 = __int_as_float(c1.y);
    ax += v0 * s0.x + v1 * s1.x;
    ay += v0 * s0.y + v1 * s1.y;
  }
  if (j < end) {
    int2 c0 = csr[j];
    float2 s0 = *(const float2*)&support[(size_t)c0.x * HIDDEN + lane * 2];
    float v0 = __int_as_float(c0.y);
    ax += v0 * s0.x;
    ay += v0 * s0.y;
  }
  const unsigned i0 = (unsigned)row * HIDDEN + lane * 2;
  float vx = fmaxf(ax + b1[lane * 2], 0.f);
  float vy = fmaxf(ay + b1[lane * 2 + 1], 0.f);
  float2 r;
  r.x = (threefry_bits(i0) >> 31) ? 0.f : 2.f * vx;
  r.y = (threefry_bits(i0 + 1) >> 31) ? 0.f : 2.f * vy;
  *(float2*)&h[i0] = r;
}

// ---------------------------------------------------------------------------
// GEMM2: h2[50000,40] = h[50000,128] @ W2[128,40].
// ---------------------------------------------------------------------------
__global__ __launch_bounds__(256) void gemm2_kernel(
    const float* __restrict__ h, const float* __restrict__ W2,
    float* __restrict__ h2) {
  __shared__ float Hs[64][132];
  __shared__ float Ws[40][132];
  const int t = threadIdx.x;
  const int node_base = blockIdx.x * 64;
#pragma unroll
  for (int i = 0; i < 8; i++) {
    int l = t + i * 256;
    int nloc = l >> 5, kq = l & 31;
    int n = node_base + nloc;
    if (n >= N_NODES) n = N_NODES - 1;
    float4 v = *(const float4*)&h[(size_t)n * HIDDEN + kq * 4];
    *(float4*)&Hs[nloc][kq * 4] = v;
  }
#pragma unroll
  for (int i = 0; i < 20; i++) {
    int l = t + i * 256;
    int k = l / NCLASS, f = l % NCLASS;
    Ws[f][k] = W2[l];
  }
  __syncthreads();
  const int nloc = t >> 2;
  const int fb = t & 3;
  const int n = node_base + nloc;
  float acc[10];
#pragma unroll
  for (int j = 0; j < 10; j++) acc[j] = 0.f;
  for (int k = 0; k < HIDDEN; k += 4) {
    float4 a = *(const float4*)&Hs[nloc][k];
#pragma unroll
    for (int j = 0; j < 10; j++) {
      float4 w = *(const float4*)&Ws[fb + 4 * j][k];
      acc[j] += a.x * w.x + a.y * w.y + a.z * w.z + a.w * w.w;
    }
  }
  if (n < N_NODES) {
#pragma unroll
    for (int j = 0; j < 10; j++) h2[(size_t)n * NCLASS + fb + 4 * j] = acc[j];
  }
}

// ---------------------------------------------------------------------------
// SpMM2 fused: wave per row, lanes 0..39 each own one class column.
// out[row] = relu(sum_e val*h2[col] + b2)
// ---------------------------------------------------------------------------
__global__ __launch_bounds__(256) void spmm2_fused(
    const int2* __restrict__ csr, const int* __restrict__ rowptr,
    const float* __restrict__ h2, const float* __restrict__ b2,
    float* __restrict__ out) {
  const int row = blockIdx.x * 4 + (threadIdx.x >> 6);
  const int lane = threadIdx.x & 63;
  if (lane >= NCLASS) return;
  const int beg = rowptr[row], end = rowptr[row + 1];
  float acc = 0.f;
  int j = beg;
  for (; j + 1 < end; j += 2) {
    int2 c0 = csr[j];
    int2 c1 = csr[j + 1];
    float s0 = h2[(size_t)c0.x * NCLASS + lane];
    float s1 = h2[(size_t)c1.x * NCLASS + lane];
    acc += __int_as_float(c0.y) * s0 + __int_as_float(c1.y) * s1;
  }
  if (j < end) {
    int2 c0 = csr[j];
    acc += __int_as_float(c0.y) * h2[(size_t)c0.x * NCLASS + lane];
  }
  out[(size_t)row * NCLASS + lane] = fmaxf(acc + b2[lane], 0.f);
}

extern "C" void kernel_launch(void* const* d_in, const int* in_sizes, int n_in,
                              void* d_out, int out_size, void* d_ws,
                              size_t ws_size, hipStream_t stream) {
  const float* x     = (const float*)d_in[0];
  const int*   erow  = (const int*)d_in[1];
  const int*   ecol  = (const int*)d_in[2];
  const float* evals = (const float*)d_in[3];
  const float* W1    = (const float*)d_in[4];
  const float* b1    = (const float*)d_in[5];
  const float* W2    = (const float*)d_in[6];
  const float* b2    = (const float*)d_in[7];
  float* out = (float*)d_out;

  // ws layout: support[6.4M f] | h[6.4M f] | csr[1.6M int2] | rowptr | cursor
  // h2 (50000x40 f, 8 MB) aliases the support region (support dead by then).
  float* support = (float*)d_ws;
  float* h   = support + (size_t)N_NODES * HIDDEN;
  int2*  csr = (int2*)(h + (size_t)N_NODES * HIDDEN);
  int* rowptr = (int*)(csr + N_EDGES);
  int* cursor = rowptr + (N_NODES + 1);
  float* h2 = support;  // alias

  hipMemsetAsync(cursor, 0, N_NODES * sizeof(int), stream);  // deg counters

  // CSR build (deg lives in `cursor` during hist, rewritten by scan)
  hist_kernel<<<N_EDGES / 256, 256, 0, stream>>>(erow, cursor);
  scan_kernel<<<1, 1024, 0, stream>>>(cursor, rowptr, cursor);
  // note: scan reads deg & writes cursor in-place (read-before-write per elem)
  scatter_kernel<<<N_EDGES / 256, 256, 0, stream>>>(erow, ecol, evals, cursor,
                                                    csr);

  gemm1_kernel<<<(N_NODES + 127) / 128, 256, 0, stream>>>(x, W1, support);
  spmm1_fused<<<N_NODES / 4, 256, 0, stream>>>(csr, rowptr, support, b1, h);
  gemm2_kernel<<<(N_NODES + 63) / 64, 256, 0, stream>>>(h, W2, h2);
  spmm2_fused<<<N_NODES / 4, 256, 0, stream>>>(csr, rowptr, h2, b2, out);
}

// Round 4
// 658.303 us; speedup vs baseline: 6.0305x; 1.1721x over previous
//
#include <hip/hip_runtime.h>
#include <hip/hip_bf16.h>

#define N_NODES 50000
#define N_EDGES 1600000
#define NFEAT   512
#define HIDDEN  128
#define NCLASS  40

typedef short short8 __attribute__((ext_vector_type(8)));
typedef float f32x4  __attribute__((ext_vector_type(4)));

// bf16 bits (RNE) from float
__device__ __forceinline__ unsigned short f2bu(float f) {
  __hip_bfloat16 h = __float2bfloat16(f);
  return *reinterpret_cast<unsigned short*>(&h);
}

// ---------------------------------------------------------------------------
// JAX threefry2x32, key (0,42), partitionable: bits[i] = o0^o1 of ctr (0,i).
// keep iff (bits>>31)==0.  (verified r2/r3: absmax 0.25)
// ---------------------------------------------------------------------------
__device__ __forceinline__ unsigned rotl32(unsigned x, int n) {
  return (x << n) | (x >> (32 - n));
}

__device__ __forceinline__ unsigned threefry_bits(unsigned x1) {
  unsigned x0 = 0u;
  const unsigned ks0 = 0u, ks1 = 42u, ks2 = 0x1BD11BDAu ^ 42u;
  x0 += ks0; x1 += ks1;
#define TFR(r) { x0 += x1; x1 = rotl32(x1, (r)); x1 ^= x0; }
  TFR(13) TFR(15) TFR(26) TFR(6)
  x0 += ks1; x1 += ks2 + 1u;
  TFR(17) TFR(29) TFR(16) TFR(24)
  x0 += ks2; x1 += ks0 + 2u;
  TFR(13) TFR(15) TFR(26) TFR(6)
  x0 += ks0; x1 += ks1 + 3u;
  TFR(17) TFR(29) TFR(16) TFR(24)
  x0 += ks1; x1 += ks2 + 4u;
  TFR(13) TFR(15) TFR(26) TFR(6)
  x0 += ks2; x1 += ks0 + 5u;
#undef TFR
  return x0 ^ x1;
}

// ---------------------------------------------------------------------------
// CSR build: histogram -> single-block scan -> scatter.  (unchanged from r3)
// ---------------------------------------------------------------------------
__global__ __launch_bounds__(256) void hist_kernel(
    const int* __restrict__ erow, int* __restrict__ deg) {
  unsigned e = blockIdx.x * 256 + threadIdx.x;
  atomicAdd(&deg[erow[e]], 1);
}

__global__ __launch_bounds__(1024) void scan_kernel(
    const int* __restrict__ deg, int* __restrict__ rowptr,
    int* __restrict__ cursor) {
  __shared__ int s[1024];
  const int t = threadIdx.x;
  const int chunk = (N_NODES + 1023) / 1024;  // 49
  const int lo = t * chunk;
  const int hi = min(lo + chunk, N_NODES);
  int sum = 0;
  for (int i = lo; i < hi; i++) sum += deg[i];
  s[t] = sum;
  __syncthreads();
  for (int off = 1; off < 1024; off <<= 1) {
    int v = (t >= off) ? s[t - off] : 0;
    __syncthreads();
    s[t] += v;
    __syncthreads();
  }
  int run = (t == 0) ? 0 : s[t - 1];
  for (int i = lo; i < hi; i++) {
    int d = deg[i];  // read-before-write (cursor aliases deg)
    rowptr[i] = run;
    cursor[i] = run;
    run += d;
  }
  if (t == 1023) rowptr[N_NODES] = N_EDGES;
}

__global__ __launch_bounds__(256) void scatter_kernel(
    const int* __restrict__ erow, const int* __restrict__ ecol,
    const float* __restrict__ evals, int* __restrict__ cursor,
    int2* __restrict__ csr) {
  unsigned e = blockIdx.x * 256 + threadIdx.x;
  int r = erow[e];
  int p = atomicAdd(&cursor[r], 1);
  csr[p] = make_int2(ecol[e], __float_as_int(evals[e]));
}

// ---------------------------------------------------------------------------
// W1T[n][k] = bf16(W1[k][n])  (128 x 512 bf16) — B-operand K-contiguous.
// ---------------------------------------------------------------------------
__global__ __launch_bounds__(256) void w1t_kernel(
    const float* __restrict__ W1, unsigned short* __restrict__ W1T) {
  int id = blockIdx.x * 256 + threadIdx.x;  // 65536 exact
  int n = id & 127, k = id >> 7;
  W1T[n * NFEAT + k] = f2bu(W1[k * HIDDEN + n]);
}

// ---------------------------------------------------------------------------
// GEMM1 (MFMA bf16): support[50000,128] = bf16(x) @ bf16(W1), fp32 acc.
// 128x128 tile, BK=32. 4 waves: wave w -> 64x64 quadrant (4x4 of 16x16x32).
// LDS chunk layout [q][row] -> frag reads are lane-contiguous (no conflicts).
// A-frag: A[m=lane&15][k=quad*8+j]; B-frag: B[k=quad*8+j][n=lane&15];
// D: col=lane&15, row=quad*4+reg   (guide §3, m89/m91-verified mapping).
// ---------------------------------------------------------------------------
__global__ __launch_bounds__(256) void gemm1_mfma(
    const float* __restrict__ x, const unsigned short* __restrict__ W1T,
    unsigned short* __restrict__ support) {
  __shared__ short8 As[512];  // chunk = q*128 + row
  __shared__ short8 Bs[512];  // chunk = q*128 + col
  const int t = threadIdx.x;
  const int lane = t & 63;
  const int w = t >> 6;
  const int quad = lane >> 4;
  const int l15 = lane & 15;
  const int node_base = blockIdx.x * 128;
  const int mbase = (w >> 1) * 64;
  const int nbase = (w & 1) * 64;

  f32x4 acc[4][4] = {};

  for (int k0 = 0; k0 < NFEAT; k0 += 32) {
#pragma unroll
    for (int i = 0; i < 2; i++) {
      int lin = i * 256 + t;        // 0..511
      int n = lin >> 2, q = lin & 3;
      int row = node_base + n;
      if (row >= N_NODES) row = N_NODES - 1;
      const float* src = &x[(size_t)row * NFEAT + k0 + q * 8];
      float4 a = *(const float4*)src;
      float4 b = *(const float4*)(src + 4);
      short8 p;
      p[0] = (short)f2bu(a.x); p[1] = (short)f2bu(a.y);
      p[2] = (short)f2bu(a.z); p[3] = (short)f2bu(a.w);
      p[4] = (short)f2bu(b.x); p[5] = (short)f2bu(b.y);
      p[6] = (short)f2bu(b.z); p[7] = (short)f2bu(b.w);
      As[q * 128 + n] = p;
      Bs[q * 128 + n] = *(const short8*)&W1T[(size_t)n * NFEAT + k0 + q * 8];
    }
    __syncthreads();
    short8 af[4], bfr[4];
#pragma unroll
    for (int mt = 0; mt < 4; mt++)
      af[mt] = As[quad * 128 + mbase + mt * 16 + l15];
#pragma unroll
    for (int nt = 0; nt < 4; nt++)
      bfr[nt] = Bs[quad * 128 + nbase + nt * 16 + l15];
#pragma unroll
    for (int mt = 0; mt < 4; mt++)
#pragma unroll
      for (int nt = 0; nt < 4; nt++)
        acc[mt][nt] = __builtin_amdgcn_mfma_f32_16x16x32_bf16(
            af[mt], bfr[nt], acc[mt][nt], 0, 0, 0);
    __syncthreads();
  }

#pragma unroll
  for (int mt = 0; mt < 4; mt++)
#pragma unroll
    for (int nt = 0; nt < 4; nt++)
#pragma unroll
      for (int r = 0; r < 4; r++) {
        int row = node_base + mbase + mt * 16 + quad * 4 + r;
        int col = nbase + nt * 16 + l15;
        if (row < N_NODES)
          support[(size_t)row * HIDDEN + col] = f2bu(acc[mt][nt][r]);
      }
}

// ---------------------------------------------------------------------------
// SpMM1 fused: wave per row, lane owns cols (2l,2l+1); support bf16 gather.
// h[row] = bf16(dropout(relu(sum val*support[col] + b1)))
// ---------------------------------------------------------------------------
__global__ __launch_bounds__(256) void spmm1_fused(
    const int2* __restrict__ csr, const int* __restrict__ rowptr,
    const unsigned* __restrict__ sup,  // support rows = 64 uints (bf162)
    const float* __restrict__ b1, unsigned* __restrict__ h) {
  const int row = blockIdx.x * 4 + (threadIdx.x >> 6);
  const int lane = threadIdx.x & 63;
  const int beg = rowptr[row], end = rowptr[row + 1];
  float ax = 0.f, ay = 0.f;
  int j = beg;
  for (; j + 1 < end; j += 2) {
    int2 c0 = csr[j], c1 = csr[j + 1];
    unsigned u0 = sup[(unsigned)c0.x * 64 + lane];
    unsigned u1 = sup[(unsigned)c1.x * 64 + lane];
    float v0 = __int_as_float(c0.y), v1 = __int_as_float(c1.y);
    ax += v0 * __uint_as_float(u0 << 16) + v1 * __uint_as_float(u1 << 16);
    ay += v0 * __uint_as_float(u0 & 0xffff0000u) +
          v1 * __uint_as_float(u1 & 0xffff0000u);
  }
  if (j < end) {
    int2 c0 = csr[j];
    unsigned u0 = sup[(unsigned)c0.x * 64 + lane];
    float v0 = __int_as_float(c0.y);
    ax += v0 * __uint_as_float(u0 << 16);
    ay += v0 * __uint_as_float(u0 & 0xffff0000u);
  }
  const unsigned i0 = (unsigned)row * HIDDEN + lane * 2;
  float vx = fmaxf(ax + b1[lane * 2], 0.f);
  float vy = fmaxf(ay + b1[lane * 2 + 1], 0.f);
  vx = (threefry_bits(i0) >> 31) ? 0.f : 2.f * vx;
  vy = (threefry_bits(i0 + 1) >> 31) ? 0.f : 2.f * vy;
  h[(unsigned)row * 64 + lane] = (unsigned)f2bu(vx) | ((unsigned)f2bu(vy) << 16);
}

// ---------------------------------------------------------------------------
// GEMM2: h2[50000,40] = h(bf16)[50000,128] @ W2[128,40], fp32 compute,
// bf16 output. 64 nodes/block.
// ---------------------------------------------------------------------------
__global__ __launch_bounds__(256) void gemm2_kernel(
    const uint4* __restrict__ h,  // rows = 16 uint4 (8 bf16 each)
    const float* __restrict__ W2, unsigned short* __restrict__ h2) {
  __shared__ float Hs[64][132];
  __shared__ float Ws[40][132];
  const int t = threadIdx.x;
  const int node_base = blockIdx.x * 64;
#pragma unroll
  for (int i = 0; i < 4; i++) {
    int lin = i * 256 + t;            // 0..1023 chunks of 8 bf16
    int nloc = lin >> 4, c8 = lin & 15;
    int n = node_base + nloc;
    if (n >= N_NODES) n = N_NODES - 1;
    uint4 u = h[(size_t)n * 16 + c8];
    float* d = &Hs[nloc][c8 * 8];
    d[0] = __uint_as_float(u.x << 16); d[1] = __uint_as_float(u.x & 0xffff0000u);
    d[2] = __uint_as_float(u.y << 16); d[3] = __uint_as_float(u.y & 0xffff0000u);
    d[4] = __uint_as_float(u.z << 16); d[5] = __uint_as_float(u.z & 0xffff0000u);
    d[6] = __uint_as_float(u.w << 16); d[7] = __uint_as_float(u.w & 0xffff0000u);
  }
#pragma unroll
  for (int i = 0; i < 20; i++) {
    int l = t + i * 256;  // 0..5119
    int k = l / NCLASS, f = l % NCLASS;
    Ws[f][k] = W2[l];
  }
  __syncthreads();
  const int nloc = t >> 2;
  const int fb = t & 3;
  const int n = node_base + nloc;
  float acc[10];
#pragma unroll
  for (int j = 0; j < 10; j++) acc[j] = 0.f;
  for (int k = 0; k < HIDDEN; k += 4) {
    float4 a = *(const float4*)&Hs[nloc][k];
#pragma unroll
    for (int j = 0; j < 10; j++) {
      float4 wv = *(const float4*)&Ws[fb + 4 * j][k];
      acc[j] += a.x * wv.x + a.y * wv.y + a.z * wv.z + a.w * wv.w;
    }
  }
  if (n < N_NODES) {
#pragma unroll
    for (int j = 0; j < 10; j++)
      h2[(size_t)n * NCLASS + fb + 4 * j] = f2bu(acc[j]);
  }
}

// ---------------------------------------------------------------------------
// SpMM2 fused: wave per row, 2 edges per iteration (lane halves), h2 bf16.
// lane half h, il=lane&31 (<20): cols (2*il, 2*il+1). shfl_xor(32) combine.
// ---------------------------------------------------------------------------
__global__ __launch_bounds__(256) void spmm2_fused(
    const int2* __restrict__ csr, const int* __restrict__ rowptr,
    const unsigned* __restrict__ h2u,  // rows = 20 uints
    const float* __restrict__ b2, float* __restrict__ out) {
  const int row = blockIdx.x * 4 + (threadIdx.x >> 6);
  const int lane = threadIdx.x & 63;
  const int half = lane >> 5;
  const int il = lane & 31;
  const unsigned ilc = (il < 20) ? (unsigned)il : 19u;
  const int beg = rowptr[row], end = rowptr[row + 1];
  float ax = 0.f, ay = 0.f;
  for (int j = beg + half; j < end; j += 2) {
    int2 c = csr[j];
    unsigned u = h2u[(unsigned)c.x * 20 + ilc];
    float v = __int_as_float(c.y);
    ax += v * __uint_as_float(u << 16);
    ay += v * __uint_as_float(u & 0xffff0000u);
  }
  ax += __shfl_xor(ax, 32);
  ay += __shfl_xor(ay, 32);
  if (half == 0 && il < 20) {
    float2 r;
    r.x = fmaxf(ax + b2[il * 2], 0.f);
    r.y = fmaxf(ay + b2[il * 2 + 1], 0.f);
    *(float2*)&out[(unsigned)row * NCLASS + il * 2] = r;
  }
}

extern "C" void kernel_launch(void* const* d_in, const int* in_sizes, int n_in,
                              void* d_out, int out_size, void* d_ws,
                              size_t ws_size, hipStream_t stream) {
  const float* x     = (const float*)d_in[0];
  const int*   erow  = (const int*)d_in[1];
  const int*   ecol  = (const int*)d_in[2];
  const float* evals = (const float*)d_in[3];
  const float* W1    = (const float*)d_in[4];
  const float* b1    = (const float*)d_in[5];
  const float* W2    = (const float*)d_in[6];
  const float* b2    = (const float*)d_in[7];
  float* out = (float*)d_out;

  // ws layout (bytes):
  // support bf16 12.8M | h bf16 12.8M | h2 bf16 4M | W1T 128K | csr 12.8M |
  // rowptr | cursor  (~42.8 MB total)
  char* base = (char*)d_ws;
  unsigned short* support = (unsigned short*)base;
  unsigned short* h   = (unsigned short*)(base + 12800000);
  unsigned short* h2  = (unsigned short*)(base + 25600000);
  unsigned short* W1T = (unsigned short*)(base + 29600000);
  int2* csr   = (int2*)(base + 29731072);
  int* rowptr = (int*)(base + 29731072 + (size_t)N_EDGES * 8);
  int* cursor = rowptr + (N_NODES + 1);

  hipMemsetAsync(cursor, 0, N_NODES * sizeof(int), stream);

  hist_kernel<<<N_EDGES / 256, 256, 0, stream>>>(erow, cursor);
  scan_kernel<<<1, 1024, 0, stream>>>(cursor, rowptr, cursor);
  scatter_kernel<<<N_EDGES / 256, 256, 0, stream>>>(erow, ecol, evals, cursor,
                                                    csr);

  w1t_kernel<<<256, 256, 0, stream>>>(W1, W1T);
  gemm1_mfma<<<(N_NODES + 127) / 128, 256, 0, stream>>>(x, W1T, support);
  spmm1_fused<<<N_NODES / 4, 256, 0, stream>>>(csr, rowptr, (const unsigned*)support,
                                               b1, (unsigned*)h);
  gemm2_kernel<<<(N_NODES + 63) / 64, 256, 0, stream>>>((const uint4*)h, W2, h2);
  spmm2_fused<<<N_NODES / 4, 256, 0, stream>>>(csr, rowptr, (const unsigned*)h2,
                                               b2, out);
}

// Round 5
// 592.023 us; speedup vs baseline: 6.7056x; 1.1120x over previous
//
#include <hip/hip_runtime.h>
#include <hip/hip_bf16.h>

#define N_NODES 50000
#define N_EDGES 1600000
#define NFEAT   512
#define HIDDEN  128
#define NCLASS  40

typedef short short8 __attribute__((ext_vector_type(8)));
typedef float f32x4  __attribute__((ext_vector_type(4)));

// bf16 bits (RNE) from float
__device__ __forceinline__ unsigned short f2bu(float f) {
  __hip_bfloat16 h = __float2bfloat16(f);
  return *reinterpret_cast<unsigned short*>(&h);
}

// ---------------------------------------------------------------------------
// JAX threefry2x32, key (0,42), partitionable: bits[i] = o0^o1 of ctr (0,i).
// keep iff (bits>>31)==0.  (verified r2-r4)
// ---------------------------------------------------------------------------
__device__ __forceinline__ unsigned rotl32(unsigned x, int n) {
  return (x << n) | (x >> (32 - n));
}

__device__ __forceinline__ unsigned threefry_bits(unsigned x1) {
  unsigned x0 = 0u;
  const unsigned ks0 = 0u, ks1 = 42u, ks2 = 0x1BD11BDAu ^ 42u;
  x0 += ks0; x1 += ks1;
#define TFR(r) { x0 += x1; x1 = rotl32(x1, (r)); x1 ^= x0; }
  TFR(13) TFR(15) TFR(26) TFR(6)
  x0 += ks1; x1 += ks2 + 1u;
  TFR(17) TFR(29) TFR(16) TFR(24)
  x0 += ks2; x1 += ks0 + 2u;
  TFR(13) TFR(15) TFR(26) TFR(6)
  x0 += ks0; x1 += ks1 + 3u;
  TFR(17) TFR(29) TFR(16) TFR(24)
  x0 += ks1; x1 += ks2 + 4u;
  TFR(13) TFR(15) TFR(26) TFR(6)
  x0 += ks2; x1 += ks0 + 5u;
#undef TFR
  return x0 ^ x1;
}

// ---------------------------------------------------------------------------
// CSR build: histogram -> single-block scan -> 2-pass scatter (packed 4B).
// ---------------------------------------------------------------------------
__global__ __launch_bounds__(256) void hist_kernel(
    const int* __restrict__ erow, int* __restrict__ deg) {
  unsigned e = blockIdx.x * 256 + threadIdx.x;
  atomicAdd(&deg[erow[e]], 1);
}

__global__ __launch_bounds__(1024) void scan_kernel(
    const int* __restrict__ deg, int* __restrict__ rowptr,
    int* __restrict__ cursor) {
  __shared__ int s[1024];
  const int t = threadIdx.x;
  const int chunk = (N_NODES + 1023) / 1024;  // 49
  const int lo = t * chunk;
  const int hi = min(lo + chunk, N_NODES);
  int sum = 0;
  for (int i = lo; i < hi; i++) sum += deg[i];
  s[t] = sum;
  __syncthreads();
  for (int off = 1; off < 1024; off <<= 1) {
    int v = (t >= off) ? s[t - off] : 0;
    __syncthreads();
    s[t] += v;
    __syncthreads();
  }
  int run = (t == 0) ? 0 : s[t - 1];
  for (int i = lo; i < hi; i++) {
    int d = deg[i];  // read-before-write (cursor aliases deg)
    rowptr[i] = run;
    cursor[i] = run;
    run += d;
  }
  if (t == 1023) rowptr[N_NODES] = N_EDGES;
}

// packed csr entry: col (low 16) | bf16(val) (high 16). Row-range pass keeps
// the pass's write region (~3.2 MB) resident in each XCD L2 -> write merging.
__global__ __launch_bounds__(256) void scatter_kernel(
    const int* __restrict__ erow, const int* __restrict__ ecol,
    const float* __restrict__ evals, int* __restrict__ cursor,
    unsigned* __restrict__ csr, int rowLo, int rowHi) {
  unsigned e = blockIdx.x * 256 + threadIdx.x;
  int r = erow[e];
  if (r < rowLo || r >= rowHi) return;
  int p = atomicAdd(&cursor[r], 1);
  csr[p] = (unsigned)ecol[e] | ((unsigned)f2bu(evals[e]) << 16);
}

// ---------------------------------------------------------------------------
// W1T[n][k] = bf16(W1[k][n])  (128 x 512 bf16)
// ---------------------------------------------------------------------------
__global__ __launch_bounds__(256) void w1t_kernel(
    const float* __restrict__ W1, unsigned short* __restrict__ W1T) {
  int id = blockIdx.x * 256 + threadIdx.x;  // 65536 exact
  int n = id & 127, k = id >> 7;
  W1T[n * NFEAT + k] = f2bu(W1[k * HIDDEN + n]);
}

// ---------------------------------------------------------------------------
// GEMM1 (MFMA bf16): support = bf16(x) @ bf16(W1), fp32 acc. (r4-verified)
// ---------------------------------------------------------------------------
__global__ __launch_bounds__(256) void gemm1_mfma(
    const float* __restrict__ x, const unsigned short* __restrict__ W1T,
    unsigned short* __restrict__ support) {
  __shared__ short8 As[512];  // chunk = q*128 + row
  __shared__ short8 Bs[512];  // chunk = q*128 + col
  const int t = threadIdx.x;
  const int lane = t & 63;
  const int w = t >> 6;
  const int quad = lane >> 4;
  const int l15 = lane & 15;
  const int node_base = blockIdx.x * 128;
  const int mbase = (w >> 1) * 64;
  const int nbase = (w & 1) * 64;

  f32x4 acc[4][4] = {};

  for (int k0 = 0; k0 < NFEAT; k0 += 32) {
#pragma unroll
    for (int i = 0; i < 2; i++) {
      int lin = i * 256 + t;        // 0..511
      int n = lin >> 2, q = lin & 3;
      int row = node_base + n;
      if (row >= N_NODES) row = N_NODES - 1;
      const float* src = &x[(size_t)row * NFEAT + k0 + q * 8];
      float4 a = *(const float4*)src;
      float4 b = *(const float4*)(src + 4);
      short8 p;
      p[0] = (short)f2bu(a.x); p[1] = (short)f2bu(a.y);
      p[2] = (short)f2bu(a.z); p[3] = (short)f2bu(a.w);
      p[4] = (short)f2bu(b.x); p[5] = (short)f2bu(b.y);
      p[6] = (short)f2bu(b.z); p[7] = (short)f2bu(b.w);
      As[q * 128 + n] = p;
      Bs[q * 128 + n] = *(const short8*)&W1T[(size_t)n * NFEAT + k0 + q * 8];
    }
    __syncthreads();
    short8 af[4], bfr[4];
#pragma unroll
    for (int mt = 0; mt < 4; mt++)
      af[mt] = As[quad * 128 + mbase + mt * 16 + l15];
#pragma unroll
    for (int nt = 0; nt < 4; nt++)
      bfr[nt] = Bs[quad * 128 + nbase + nt * 16 + l15];
#pragma unroll
    for (int mt = 0; mt < 4; mt++)
#pragma unroll
      for (int nt = 0; nt < 4; nt++)
        acc[mt][nt] = __builtin_amdgcn_mfma_f32_16x16x32_bf16(
            af[mt], bfr[nt], acc[mt][nt], 0, 0, 0);
    __syncthreads();
  }

#pragma unroll
  for (int mt = 0; mt < 4; mt++)
#pragma unroll
    for (int nt = 0; nt < 4; nt++)
#pragma unroll
      for (int r = 0; r < 4; r++) {
        int row = node_base + mbase + mt * 16 + quad * 4 + r;
        int col = nbase + nt * 16 + l15;
        if (row < N_NODES)
          support[(size_t)row * HIDDEN + col] = f2bu(acc[mt][nt][r]);
      }
}

// ---------------------------------------------------------------------------
// SpMM1 fused: wave per row, 4-edge unroll. csr packed 4B.
// h[row] = bf16(dropout(relu(sum val*support[col] + b1)))
// ---------------------------------------------------------------------------
__global__ __launch_bounds__(256) void spmm1_fused(
    const unsigned* __restrict__ csr, const int* __restrict__ rowptr,
    const unsigned* __restrict__ sup,  // support rows = 64 uints (bf162)
    const float* __restrict__ b1, unsigned* __restrict__ h) {
  const int row = blockIdx.x * 4 + (threadIdx.x >> 6);
  const int lane = threadIdx.x & 63;
  const int beg = rowptr[row], end = rowptr[row + 1];
  float ax = 0.f, ay = 0.f;
  int j = beg;
  for (; j + 3 < end; j += 4) {
    unsigned p0 = csr[j], p1 = csr[j + 1], p2 = csr[j + 2], p3 = csr[j + 3];
    unsigned u0 = sup[(p0 & 0xffffu) * 64 + lane];
    unsigned u1 = sup[(p1 & 0xffffu) * 64 + lane];
    unsigned u2 = sup[(p2 & 0xffffu) * 64 + lane];
    unsigned u3 = sup[(p3 & 0xffffu) * 64 + lane];
    float v0 = __uint_as_float(p0 & 0xffff0000u);
    float v1 = __uint_as_float(p1 & 0xffff0000u);
    float v2 = __uint_as_float(p2 & 0xffff0000u);
    float v3 = __uint_as_float(p3 & 0xffff0000u);
    ax += v0 * __uint_as_float(u0 << 16) + v1 * __uint_as_float(u1 << 16) +
          v2 * __uint_as_float(u2 << 16) + v3 * __uint_as_float(u3 << 16);
    ay += v0 * __uint_as_float(u0 & 0xffff0000u) +
          v1 * __uint_as_float(u1 & 0xffff0000u) +
          v2 * __uint_as_float(u2 & 0xffff0000u) +
          v3 * __uint_as_float(u3 & 0xffff0000u);
  }
  for (; j < end; j++) {
    unsigned p0 = csr[j];
    unsigned u0 = sup[(p0 & 0xffffu) * 64 + lane];
    float v0 = __uint_as_float(p0 & 0xffff0000u);
    ax += v0 * __uint_as_float(u0 << 16);
    ay += v0 * __uint_as_float(u0 & 0xffff0000u);
  }
  const unsigned i0 = (unsigned)row * HIDDEN + lane * 2;
  float vx = fmaxf(ax + b1[lane * 2], 0.f);
  float vy = fmaxf(ay + b1[lane * 2 + 1], 0.f);
  vx = (threefry_bits(i0) >> 31) ? 0.f : 2.f * vx;
  vy = (threefry_bits(i0 + 1) >> 31) ? 0.f : 2.f * vy;
  h[(unsigned)row * 64 + lane] = (unsigned)f2bu(vx) | ((unsigned)f2bu(vy) << 16);
}

// ---------------------------------------------------------------------------
// GEMM2: h2[50000,40] = h(bf16) @ W2, fp32 compute, bf16 out. (r4-verified)
// ---------------------------------------------------------------------------
__global__ __launch_bounds__(256) void gemm2_kernel(
    const uint4* __restrict__ h,  // rows = 16 uint4 (8 bf16 each)
    const float* __restrict__ W2, unsigned short* __restrict__ h2) {
  __shared__ float Hs[64][132];
  __shared__ float Ws[40][132];
  const int t = threadIdx.x;
  const int node_base = blockIdx.x * 64;
#pragma unroll
  for (int i = 0; i < 4; i++) {
    int lin = i * 256 + t;
    int nloc = lin >> 4, c8 = lin & 15;
    int n = node_base + nloc;
    if (n >= N_NODES) n = N_NODES - 1;
    uint4 u = h[(size_t)n * 16 + c8];
    float* d = &Hs[nloc][c8 * 8];
    d[0] = __uint_as_float(u.x << 16); d[1] = __uint_as_float(u.x & 0xffff0000u);
    d[2] = __uint_as_float(u.y << 16); d[3] = __uint_as_float(u.y & 0xffff0000u);
    d[4] = __uint_as_float(u.z << 16); d[5] = __uint_as_float(u.z & 0xffff0000u);
    d[6] = __uint_as_float(u.w << 16); d[7] = __uint_as_float(u.w & 0xffff0000u);
  }
#pragma unroll
  for (int i = 0; i < 20; i++) {
    int l = t + i * 256;
    int k = l / NCLASS, f = l % NCLASS;
    Ws[f][k] = W2[l];
  }
  __syncthreads();
  const int nloc = t >> 2;
  const int fb = t & 3;
  const int n = node_base + nloc;
  float acc[10];
#pragma unroll
  for (int j = 0; j < 10; j++) acc[j] = 0.f;
  for (int k = 0; k < HIDDEN; k += 4) {
    float4 a = *(const float4*)&Hs[nloc][k];
#pragma unroll
    for (int j = 0; j < 10; j++) {
      float4 wv = *(const float4*)&Ws[fb + 4 * j][k];
      acc[j] += a.x * wv.x + a.y * wv.y + a.z * wv.z + a.w * wv.w;
    }
  }
  if (n < N_NODES) {
#pragma unroll
    for (int j = 0; j < 10; j++)
      h2[(size_t)n * NCLASS + fb + 4 * j] = f2bu(acc[j]);
  }
}

// ---------------------------------------------------------------------------
// SpMM2 fused: wave per row, 4 edges in flight (half-split x 2-unroll).
// ---------------------------------------------------------------------------
__global__ __launch_bounds__(256) void spmm2_fused(
    const unsigned* __restrict__ csr, const int* __restrict__ rowptr,
    const unsigned* __restrict__ h2u,  // rows = 20 uints
    const float* __restrict__ b2, float* __restrict__ out) {
  const int row = blockIdx.x * 4 + (threadIdx.x >> 6);
  const int lane = threadIdx.x & 63;
  const int half = lane >> 5;
  const int il = lane & 31;
  const unsigned ilc = (il < 20) ? (unsigned)il : 19u;
  const int beg = rowptr[row], end = rowptr[row + 1];
  float ax = 0.f, ay = 0.f;
  int j = beg + half;
  for (; j + 2 < end; j += 4) {  // edges j and j+2 (this half's parity)
    unsigned p0 = csr[j], p1 = csr[j + 2];
    unsigned u0 = h2u[(p0 & 0xffffu) * 20 + ilc];
    unsigned u1 = h2u[(p1 & 0xffffu) * 20 + ilc];
    float v0 = __uint_as_float(p0 & 0xffff0000u);
    float v1 = __uint_as_float(p1 & 0xffff0000u);
    ax += v0 * __uint_as_float(u0 << 16) + v1 * __uint_as_float(u1 << 16);
    ay += v0 * __uint_as_float(u0 & 0xffff0000u) +
          v1 * __uint_as_float(u1 & 0xffff0000u);
  }
  for (; j < end; j += 2) {
    unsigned p0 = csr[j];
    unsigned u0 = h2u[(p0 & 0xffffu) * 20 + ilc];
    float v0 = __uint_as_float(p0 & 0xffff0000u);
    ax += v0 * __uint_as_float(u0 << 16);
    ay += v0 * __uint_as_float(u0 & 0xffff0000u);
  }
  ax += __shfl_xor(ax, 32);
  ay += __shfl_xor(ay, 32);
  if (half == 0 && il < 20) {
    float2 r;
    r.x = fmaxf(ax + b2[il * 2], 0.f);
    r.y = fmaxf(ay + b2[il * 2 + 1], 0.f);
    *(float2*)&out[(unsigned)row * NCLASS + il * 2] = r;
  }
}

extern "C" void kernel_launch(void* const* d_in, const int* in_sizes, int n_in,
                              void* d_out, int out_size, void* d_ws,
                              size_t ws_size, hipStream_t stream) {
  const float* x     = (const float*)d_in[0];
  const int*   erow  = (const int*)d_in[1];
  const int*   ecol  = (const int*)d_in[2];
  const float* evals = (const float*)d_in[3];
  const float* W1    = (const float*)d_in[4];
  const float* b1    = (const float*)d_in[5];
  const float* W2    = (const float*)d_in[6];
  const float* b2    = (const float*)d_in[7];
  float* out = (float*)d_out;

  // ws layout (bytes): support bf16 12.8M | h bf16 12.8M | h2 bf16 4M |
  // W1T 128K | csr packed 6.4M | rowptr | cursor   (~36.4 MB)
  char* base = (char*)d_ws;
  unsigned short* support = (unsigned short*)base;
  unsigned short* h   = (unsigned short*)(base + 12800000);
  unsigned short* h2  = (unsigned short*)(base + 25600000);
  unsigned short* W1T = (unsigned short*)(base + 29600000);
  unsigned* csr = (unsigned*)(base + 29731072);
  int* rowptr = (int*)(base + 29731072 + (size_t)N_EDGES * 4);
  int* cursor = rowptr + (N_NODES + 1);

  hipMemsetAsync(cursor, 0, N_NODES * sizeof(int), stream);

  hist_kernel<<<N_EDGES / 256, 256, 0, stream>>>(erow, cursor);
  scan_kernel<<<1, 1024, 0, stream>>>(cursor, rowptr, cursor);
  // 2 row-range passes: each pass's csr write region (~3.2 MB) fits per-XCD L2
  scatter_kernel<<<N_EDGES / 256, 256, 0, stream>>>(erow, ecol, evals, cursor,
                                                    csr, 0, 25000);
  scatter_kernel<<<N_EDGES / 256, 256, 0, stream>>>(erow, ecol, evals, cursor,
                                                    csr, 25000, 50000);

  w1t_kernel<<<256, 256, 0, stream>>>(W1, W1T);
  gemm1_mfma<<<(N_NODES + 127) / 128, 256, 0, stream>>>(x, W1T, support);
  spmm1_fused<<<N_NODES / 4, 256, 0, stream>>>(csr, rowptr,
                                               (const unsigned*)support, b1,
                                               (unsigned*)h);
  gemm2_kernel<<<(N_NODES + 63) / 64, 256, 0, stream>>>((const uint4*)h, W2, h2);
  spmm2_fused<<<N_NODES / 4, 256, 0, stream>>>(csr, rowptr,
                                               (const unsigned*)h2, b2, out);
}

// Round 6
// 489.998 us; speedup vs baseline: 8.1018x; 1.2082x over previous
//
#include <hip/hip_runtime.h>
#include <hip/hip_bf16.h>

#define N_NODES 50000
#define N_EDGES 1600000
#define NFEAT   512
#define HIDDEN  128
#define NCLASS  40

#define SCAN_BLOCKS 196  // ceil(50000/256)

typedef short short8 __attribute__((ext_vector_type(8)));
typedef float f32x4  __attribute__((ext_vector_type(4)));

// bf16 bits (RNE) from float
__device__ __forceinline__ unsigned short f2bu(float f) {
  __hip_bfloat16 h = __float2bfloat16(f);
  return *reinterpret_cast<unsigned short*>(&h);
}

// ---------------------------------------------------------------------------
// JAX threefry2x32, key (0,42), partitionable: bits[i] = o0^o1 of ctr (0,i).
// keep iff (bits>>31)==0.  (verified r2-r5)
// ---------------------------------------------------------------------------
__device__ __forceinline__ unsigned rotl32(unsigned x, int n) {
  return (x << n) | (x >> (32 - n));
}

__device__ __forceinline__ unsigned threefry_bits(unsigned x1) {
  unsigned x0 = 0u;
  const unsigned ks0 = 0u, ks1 = 42u, ks2 = 0x1BD11BDAu ^ 42u;
  x0 += ks0; x1 += ks1;
#define TFR(r) { x0 += x1; x1 = rotl32(x1, (r)); x1 ^= x0; }
  TFR(13) TFR(15) TFR(26) TFR(6)
  x0 += ks1; x1 += ks2 + 1u;
  TFR(17) TFR(29) TFR(16) TFR(24)
  x0 += ks2; x1 += ks0 + 2u;
  TFR(13) TFR(15) TFR(26) TFR(6)
  x0 += ks0; x1 += ks1 + 3u;
  TFR(17) TFR(29) TFR(16) TFR(24)
  x0 += ks1; x1 += ks2 + 4u;
  TFR(13) TFR(15) TFR(26) TFR(6)
  x0 += ks2; x1 += ks0 + 5u;
#undef TFR
  return x0 ^ x1;
}

// ---------------------------------------------------------------------------
// CSR build: histogram -> hierarchical scan (3 parallel kernels) ->
// 2-pass scatter (packed 4B entries).
// ---------------------------------------------------------------------------
__global__ __launch_bounds__(256) void hist_kernel(
    const int* __restrict__ erow, int* __restrict__ deg) {
  unsigned e = blockIdx.x * 256 + threadIdx.x;
  atomicAdd(&deg[erow[e]], 1);
}

// block b: blocksum[b] = sum(deg[b*256 .. b*256+255])
__global__ __launch_bounds__(256) void partial_kernel(
    const int* __restrict__ deg, int* __restrict__ blocksum) {
  const int i = blockIdx.x * 256 + threadIdx.x;
  int v = (i < N_NODES) ? deg[i] : 0;
#pragma unroll
  for (int off = 32; off >= 1; off >>= 1) v += __shfl_down(v, off);
  __shared__ int ws[4];
  if ((threadIdx.x & 63) == 0) ws[threadIdx.x >> 6] = v;
  __syncthreads();
  if (threadIdx.x == 0)
    blocksum[blockIdx.x] = ws[0] + ws[1] + ws[2] + ws[3];
}

// single block: exclusive scan of blocksum[196] in-place
__global__ __launch_bounds__(256) void scanblk_kernel(
    int* __restrict__ blocksum) {
  __shared__ int s[256];
  const int t = threadIdx.x;
  s[t] = (t < SCAN_BLOCKS) ? blocksum[t] : 0;
  __syncthreads();
#pragma unroll
  for (int off = 1; off < 256; off <<= 1) {
    int v = (t >= off) ? s[t - off] : 0;
    __syncthreads();
    s[t] += v;
    __syncthreads();
  }
  if (t < SCAN_BLOCKS) blocksum[t] = (t == 0) ? 0 : s[t - 1];  // exclusive
}

// block b: exclusive scan within chunk + blocksum[b] -> rowptr, cursor
__global__ __launch_bounds__(256) void final_kernel(
    const int* __restrict__ deg, const int* __restrict__ blocksum,
    int* __restrict__ rowptr, int* __restrict__ cursor) {
  __shared__ int s[256];
  const int t = threadIdx.x;
  const int i = blockIdx.x * 256 + t;
  const int d = (i < N_NODES) ? deg[i] : 0;
  s[t] = d;
  __syncthreads();
#pragma unroll
  for (int off = 1; off < 256; off <<= 1) {
    int v = (t >= off) ? s[t - off] : 0;
    __syncthreads();
    s[t] += v;
    __syncthreads();
  }
  if (i < N_NODES) {
    int pre = blocksum[blockIdx.x] + s[t] - d;  // exclusive prefix
    rowptr[i] = pre;
    cursor[i] = pre;
    if (i == N_NODES - 1) rowptr[N_NODES] = N_EDGES;
  }
}

// packed csr entry: col (low 16) | bf16(val) (high 16). Row-range pass keeps
// the pass's write region (~3.2 MB) resident in each XCD L2 -> write merging.
__global__ __launch_bounds__(256) void scatter_kernel(
    const int* __restrict__ erow, const int* __restrict__ ecol,
    const float* __restrict__ evals, int* __restrict__ cursor,
    unsigned* __restrict__ csr, int rowLo, int rowHi) {
  unsigned e = blockIdx.x * 256 + threadIdx.x;
  int r = erow[e];
  if (r < rowLo || r >= rowHi) return;
  int p = atomicAdd(&cursor[r], 1);
  csr[p] = (unsigned)ecol[e] | ((unsigned)f2bu(evals[e]) << 16);
}

// ---------------------------------------------------------------------------
// W1T[n][k] = bf16(W1[k][n])  (128 x 512 bf16)
// ---------------------------------------------------------------------------
__global__ __launch_bounds__(256) void w1t_kernel(
    const float* __restrict__ W1, unsigned short* __restrict__ W1T) {
  int id = blockIdx.x * 256 + threadIdx.x;  // 65536 exact
  int n = id & 127, k = id >> 7;
  W1T[n * NFEAT + k] = f2bu(W1[k * HIDDEN + n]);
}

// ---------------------------------------------------------------------------
// GEMM1 (MFMA bf16): support = bf16(x) @ bf16(W1), fp32 acc. (r4-verified)
// ---------------------------------------------------------------------------
__global__ __launch_bounds__(256) void gemm1_mfma(
    const float* __restrict__ x, const unsigned short* __restrict__ W1T,
    unsigned short* __restrict__ support) {
  __shared__ short8 As[512];  // chunk = q*128 + row
  __shared__ short8 Bs[512];  // chunk = q*128 + col
  const int t = threadIdx.x;
  const int lane = t & 63;
  const int w = t >> 6;
  const int quad = lane >> 4;
  const int l15 = lane & 15;
  const int node_base = blockIdx.x * 128;
  const int mbase = (w >> 1) * 64;
  const int nbase = (w & 1) * 64;

  f32x4 acc[4][4] = {};

  for (int k0 = 0; k0 < NFEAT; k0 += 32) {
#pragma unroll
    for (int i = 0; i < 2; i++) {
      int lin = i * 256 + t;        // 0..511
      int n = lin >> 2, q = lin & 3;
      int row = node_base + n;
      if (row >= N_NODES) row = N_NODES - 1;
      const float* src = &x[(size_t)row * NFEAT + k0 + q * 8];
      float4 a = *(const float4*)src;
      float4 b = *(const float4*)(src + 4);
      short8 p;
      p[0] = (short)f2bu(a.x); p[1] = (short)f2bu(a.y);
      p[2] = (short)f2bu(a.z); p[3] = (short)f2bu(a.w);
      p[4] = (short)f2bu(b.x); p[5] = (short)f2bu(b.y);
      p[6] = (short)f2bu(b.z); p[7] = (short)f2bu(b.w);
      As[q * 128 + n] = p;
      Bs[q * 128 + n] = *(const short8*)&W1T[(size_t)n * NFEAT + k0 + q * 8];
    }
    __syncthreads();
    short8 af[4], bfr[4];
#pragma unroll
    for (int mt = 0; mt < 4; mt++)
      af[mt] = As[quad * 128 + mbase + mt * 16 + l15];
#pragma unroll
    for (int nt = 0; nt < 4; nt++)
      bfr[nt] = Bs[quad * 128 + nbase + nt * 16 + l15];
#pragma unroll
    for (int mt = 0; mt < 4; mt++)
#pragma unroll
      for (int nt = 0; nt < 4; nt++)
        acc[mt][nt] = __builtin_amdgcn_mfma_f32_16x16x32_bf16(
            af[mt], bfr[nt], acc[mt][nt], 0, 0, 0);
    __syncthreads();
  }

#pragma unroll
  for (int mt = 0; mt < 4; mt++)
#pragma unroll
    for (int nt = 0; nt < 4; nt++)
#pragma unroll
      for (int r = 0; r < 4; r++) {
        int row = node_base + mbase + mt * 16 + quad * 4 + r;
        int col = nbase + nt * 16 + l15;
        if (row < N_NODES)
          support[(size_t)row * HIDDEN + col] = f2bu(acc[mt][nt][r]);
      }
}

// ---------------------------------------------------------------------------
// SpMM1 fused: wave per row, 4-edge unroll. csr packed 4B.
// h[row] = bf16(dropout(relu(sum val*support[col] + b1)))
// ---------------------------------------------------------------------------
__global__ __launch_bounds__(256) void spmm1_fused(
    const unsigned* __restrict__ csr, const int* __restrict__ rowptr,
    const unsigned* __restrict__ sup,  // support rows = 64 uints (bf162)
    const float* __restrict__ b1, unsigned* __restrict__ h) {
  const int row = blockIdx.x * 4 + (threadIdx.x >> 6);
  const int lane = threadIdx.x & 63;
  const int beg = rowptr[row], end = rowptr[row + 1];
  float ax = 0.f, ay = 0.f;
  int j = beg;
  for (; j + 3 < end; j += 4) {
    unsigned p0 = csr[j], p1 = csr[j + 1], p2 = csr[j + 2], p3 = csr[j + 3];
    unsigned u0 = sup[(p0 & 0xffffu) * 64 + lane];
    unsigned u1 = sup[(p1 & 0xffffu) * 64 + lane];
    unsigned u2 = sup[(p2 & 0xffffu) * 64 + lane];
    unsigned u3 = sup[(p3 & 0xffffu) * 64 + lane];
    float v0 = __uint_as_float(p0 & 0xffff0000u);
    float v1 = __uint_as_float(p1 & 0xffff0000u);
    float v2 = __uint_as_float(p2 & 0xffff0000u);
    float v3 = __uint_as_float(p3 & 0xffff0000u);
    ax += v0 * __uint_as_float(u0 << 16) + v1 * __uint_as_float(u1 << 16) +
          v2 * __uint_as_float(u2 << 16) + v3 * __uint_as_float(u3 << 16);
    ay += v0 * __uint_as_float(u0 & 0xffff0000u) +
          v1 * __uint_as_float(u1 & 0xffff0000u) +
          v2 * __uint_as_float(u2 & 0xffff0000u) +
          v3 * __uint_as_float(u3 & 0xffff0000u);
  }
  for (; j < end; j++) {
    unsigned p0 = csr[j];
    unsigned u0 = sup[(p0 & 0xffffu) * 64 + lane];
    float v0 = __uint_as_float(p0 & 0xffff0000u);
    ax += v0 * __uint_as_float(u0 << 16);
    ay += v0 * __uint_as_float(u0 & 0xffff0000u);
  }
  const unsigned i0 = (unsigned)row * HIDDEN + lane * 2;
  float vx = fmaxf(ax + b1[lane * 2], 0.f);
  float vy = fmaxf(ay + b1[lane * 2 + 1], 0.f);
  vx = (threefry_bits(i0) >> 31) ? 0.f : 2.f * vx;
  vy = (threefry_bits(i0 + 1) >> 31) ? 0.f : 2.f * vy;
  h[(unsigned)row * 64 + lane] = (unsigned)f2bu(vx) | ((unsigned)f2bu(vy) << 16);
}

// ---------------------------------------------------------------------------
// GEMM2: h2[50000,40] = h(bf16) @ W2, fp32 compute, bf16 out. (r4-verified)
// ---------------------------------------------------------------------------
__global__ __launch_bounds__(256) void gemm2_kernel(
    const uint4* __restrict__ h,  // rows = 16 uint4 (8 bf16 each)
    const float* __restrict__ W2, unsigned short* __restrict__ h2) {
  __shared__ float Hs[64][132];
  __shared__ float Ws[40][132];
  const int t = threadIdx.x;
  const int node_base = blockIdx.x * 64;
#pragma unroll
  for (int i = 0; i < 4; i++) {
    int lin = i * 256 + t;
    int nloc = lin >> 4, c8 = lin & 15;
    int n = node_base + nloc;
    if (n >= N_NODES) n = N_NODES - 1;
    uint4 u = h[(size_t)n * 16 + c8];
    float* d = &Hs[nloc][c8 * 8];
    d[0] = __uint_as_float(u.x << 16); d[1] = __uint_as_float(u.x & 0xffff0000u);
    d[2] = __uint_as_float(u.y << 16); d[3] = __uint_as_float(u.y & 0xffff0000u);
    d[4] = __uint_as_float(u.z << 16); d[5] = __uint_as_float(u.z & 0xffff0000u);
    d[6] = __uint_as_float(u.w << 16); d[7] = __uint_as_float(u.w & 0xffff0000u);
  }
#pragma unroll
  for (int i = 0; i < 20; i++) {
    int l = t + i * 256;
    int k = l / NCLASS, f = l % NCLASS;
    Ws[f][k] = W2[l];
  }
  __syncthreads();
  const int nloc = t >> 2;
  const int fb = t & 3;
  const int n = node_base + nloc;
  float acc[10];
#pragma unroll
  for (int j = 0; j < 10; j++) acc[j] = 0.f;
  for (int k = 0; k < HIDDEN; k += 4) {
    float4 a = *(const float4*)&Hs[nloc][k];
#pragma unroll
    for (int j = 0; j < 10; j++) {
      float4 wv = *(const float4*)&Ws[fb + 4 * j][k];
      acc[j] += a.x * wv.x + a.y * wv.y + a.z * wv.z + a.w * wv.w;
    }
  }
  if (n < N_NODES) {
#pragma unroll
    for (int j = 0; j < 10; j++)
      h2[(size_t)n * NCLASS + fb + 4 * j] = f2bu(acc[j]);
  }
}

// ---------------------------------------------------------------------------
// SpMM2 fused: wave per row, 4 edges in flight (half-split x 2-unroll).
// ---------------------------------------------------------------------------
__global__ __launch_bounds__(256) void spmm2_fused(
    const unsigned* __restrict__ csr, const int* __restrict__ rowptr,
    const unsigned* __restrict__ h2u,  // rows = 20 uints
    const float* __restrict__ b2, float* __restrict__ out) {
  const int row = blockIdx.x * 4 + (threadIdx.x >> 6);
  const int lane = threadIdx.x & 63;
  const int half = lane >> 5;
  const int il = lane & 31;
  const unsigned ilc = (il < 20) ? (unsigned)il : 19u;
  const int beg = rowptr[row], end = rowptr[row + 1];
  float ax = 0.f, ay = 0.f;
  int j = beg + half;
  for (; j + 2 < end; j += 4) {  // edges j and j+2 (this half's parity)
    unsigned p0 = csr[j], p1 = csr[j + 2];
    unsigned u0 = h2u[(p0 & 0xffffu) * 20 + ilc];
    unsigned u1 = h2u[(p1 & 0xffffu) * 20 + ilc];
    float v0 = __uint_as_float(p0 & 0xffff0000u);
    float v1 = __uint_as_float(p1 & 0xffff0000u);
    ax += v0 * __uint_as_float(u0 << 16) + v1 * __uint_as_float(u1 << 16);
    ay += v0 * __uint_as_float(u0 & 0xffff0000u) +
          v1 * __uint_as_float(u1 & 0xffff0000u);
  }
  for (; j < end; j += 2) {
    unsigned p0 = csr[j];
    unsigned u0 = h2u[(p0 & 0xffffu) * 20 + ilc];
    float v0 = __uint_as_float(p0 & 0xffff0000u);
    ax += v0 * __uint_as_float(u0 << 16);
    ay += v0 * __uint_as_float(u0 & 0xffff0000u);
  }
  ax += __shfl_xor(ax, 32);
  ay += __shfl_xor(ay, 32);
  if (half == 0 && il < 20) {
    float2 r;
    r.x = fmaxf(ax + b2[il * 2], 0.f);
    r.y = fmaxf(ay + b2[il * 2 + 1], 0.f);
    *(float2*)&out[(unsigned)row * NCLASS + il * 2] = r;
  }
}

extern "C" void kernel_launch(void* const* d_in, const int* in_sizes, int n_in,
                              void* d_out, int out_size, void* d_ws,
                              size_t ws_size, hipStream_t stream) {
  const float* x     = (const float*)d_in[0];
  const int*   erow  = (const int*)d_in[1];
  const int*   ecol  = (const int*)d_in[2];
  const float* evals = (const float*)d_in[3];
  const float* W1    = (const float*)d_in[4];
  const float* b1    = (const float*)d_in[5];
  const float* W2    = (const float*)d_in[6];
  const float* b2    = (const float*)d_in[7];
  float* out = (float*)d_out;

  // ws layout (bytes): support bf16 12.8M | h bf16 12.8M | h2 bf16 4M |
  // W1T 128K | csr packed 6.4M | rowptr | cursor | blocksum  (~36.4 MB)
  char* base = (char*)d_ws;
  unsigned short* support = (unsigned short*)base;
  unsigned short* h   = (unsigned short*)(base + 12800000);
  unsigned short* h2  = (unsigned short*)(base + 25600000);
  unsigned short* W1T = (unsigned short*)(base + 29600000);
  unsigned* csr = (unsigned*)(base + 29731072);
  int* rowptr = (int*)(base + 29731072 + (size_t)N_EDGES * 4);
  int* cursor = rowptr + (N_NODES + 1);
  int* blocksum = cursor + N_NODES;

  hipMemsetAsync(cursor, 0, N_NODES * sizeof(int), stream);

  hist_kernel<<<N_EDGES / 256, 256, 0, stream>>>(erow, cursor);
  // hierarchical scan: deg (in cursor) -> rowptr/cursor, all CUs busy
  partial_kernel<<<SCAN_BLOCKS, 256, 0, stream>>>(cursor, blocksum);
  scanblk_kernel<<<1, 256, 0, stream>>>(blocksum);
  final_kernel<<<SCAN_BLOCKS, 256, 0, stream>>>(cursor, blocksum, rowptr,
                                                cursor);
  // 2 row-range passes: each pass's csr write region (~3.2 MB) fits per-XCD L2
  scatter_kernel<<<N_EDGES / 256, 256, 0, stream>>>(erow, ecol, evals, cursor,
                                                    csr, 0, 25000);
  scatter_kernel<<<N_EDGES / 256, 256, 0, stream>>>(erow, ecol, evals, cursor,
                                                    csr, 25000, 50000);

  w1t_kernel<<<256, 256, 0, stream>>>(W1, W1T);
  gemm1_mfma<<<(N_NODES + 127) / 128, 256, 0, stream>>>(x, W1T, support);
  spmm1_fused<<<N_NODES / 4, 256, 0, stream>>>(csr, rowptr,
                                               (const unsigned*)support, b1,
                                               (unsigned*)h);
  gemm2_kernel<<<(N_NODES + 63) / 64, 256, 0, stream>>>((const uint4*)h, W2, h2);
  spmm2_fused<<<N_NODES / 4, 256, 0, stream>>>(csr, rowptr,
                                               (const unsigned*)h2, b2, out);
}

// Round 7
// 477.504 us; speedup vs baseline: 8.3138x; 1.0262x over previous
//
#include <hip/hip_runtime.h>
#include <hip/hip_bf16.h>

#define N_NODES 50000
#define N_EDGES 1600000
#define NFEAT   512
#define HIDDEN  128
#define NCLASS  40

#define SCAN_BLOCKS 196  // ceil(50000/256)
#define NREP 8           // atomic replicas (~XCD count)

typedef short short8 __attribute__((ext_vector_type(8)));
typedef float f32x4  __attribute__((ext_vector_type(4)));

// bf16 bits (RNE) from float
__device__ __forceinline__ unsigned short f2bu(float f) {
  __hip_bfloat16 h = __float2bfloat16(f);
  return *reinterpret_cast<unsigned short*>(&h);
}

// ---------------------------------------------------------------------------
// JAX threefry2x32, key (0,42), partitionable: bits[i] = o0^o1 of ctr (0,i).
// keep iff (bits>>31)==0.  (verified r2-r6)
// ---------------------------------------------------------------------------
__device__ __forceinline__ unsigned rotl32(unsigned x, int n) {
  return (x << n) | (x >> (32 - n));
}

__device__ __forceinline__ unsigned threefry_bits(unsigned x1) {
  unsigned x0 = 0u;
  const unsigned ks0 = 0u, ks1 = 42u, ks2 = 0x1BD11BDAu ^ 42u;
  x0 += ks0; x1 += ks1;
#define TFR(r) { x0 += x1; x1 = rotl32(x1, (r)); x1 ^= x0; }
  TFR(13) TFR(15) TFR(26) TFR(6)
  x0 += ks1; x1 += ks2 + 1u;
  TFR(17) TFR(29) TFR(16) TFR(24)
  x0 += ks2; x1 += ks0 + 2u;
  TFR(13) TFR(15) TFR(26) TFR(6)
  x0 += ks0; x1 += ks1 + 3u;
  TFR(17) TFR(29) TFR(16) TFR(24)
  x0 += ks1; x1 += ks2 + 4u;
  TFR(13) TFR(15) TFR(26) TFR(6)
  x0 += ks2; x1 += ks0 + 5u;
#undef TFR
  return x0 ^ x1;
}

// ---------------------------------------------------------------------------
// CSR build: replica histogram+pack -> hierarchical scan (also builds
// per-replica cursors) -> 2-pass scatter with replica cursors.
// Replica = blockIdx&7 (correlates with XCD on round-robin dispatch) so
// atomic lines stay in one XCD's L2 instead of bouncing device-wide.
// ---------------------------------------------------------------------------
__global__ __launch_bounds__(256) void hist_pack_kernel(
    const int* __restrict__ erow, const int* __restrict__ ecol,
    const float* __restrict__ evals, int* __restrict__ deg_r,
    unsigned* __restrict__ pval) {
  unsigned e = blockIdx.x * 256 + threadIdx.x;  // grid exact: 1.6M
  int r = erow[e];
  atomicAdd(&deg_r[(blockIdx.x & (NREP - 1)) * N_NODES + r], 1);
  pval[e] = (unsigned)ecol[e] | ((unsigned)f2bu(evals[e]) << 16);
}

// block b: blocksum[b] = sum over i in chunk of total degree
__global__ __launch_bounds__(256) void partial_kernel(
    const int* __restrict__ deg_r, int* __restrict__ blocksum) {
  const int i = blockIdx.x * 256 + threadIdx.x;
  int v = 0;
  if (i < N_NODES) {
#pragma unroll
    for (int r = 0; r < NREP; r++) v += deg_r[r * N_NODES + i];
  }
#pragma unroll
  for (int off = 32; off >= 1; off >>= 1) v += __shfl_down(v, off);
  __shared__ int ws[4];
  if ((threadIdx.x & 63) == 0) ws[threadIdx.x >> 6] = v;
  __syncthreads();
  if (threadIdx.x == 0)
    blocksum[blockIdx.x] = ws[0] + ws[1] + ws[2] + ws[3];
}

// single block: exclusive scan of blocksum[196] in-place
__global__ __launch_bounds__(256) void scanblk_kernel(
    int* __restrict__ blocksum) {
  __shared__ int s[256];
  const int t = threadIdx.x;
  s[t] = (t < SCAN_BLOCKS) ? blocksum[t] : 0;
  __syncthreads();
#pragma unroll
  for (int off = 1; off < 256; off <<= 1) {
    int v = (t >= off) ? s[t - off] : 0;
    __syncthreads();
    s[t] += v;
    __syncthreads();
  }
  if (t < SCAN_BLOCKS) blocksum[t] = (t == 0) ? 0 : s[t - 1];  // exclusive
}

// block b: in-chunk scan of total degree + blocksum -> rowptr; also writes
// per-replica cursor bases coff[r][i] = rowptr[i] + sum_{r'<r} deg_r[r'][i].
__global__ __launch_bounds__(256) void final_kernel(
    const int* __restrict__ deg_r, const int* __restrict__ blocksum,
    int* __restrict__ rowptr, int* __restrict__ coff) {
  __shared__ int s[256];
  const int t = threadIdx.x;
  const int i = blockIdx.x * 256 + t;
  int d[NREP];
  int tot = 0;
  if (i < N_NODES) {
#pragma unroll
    for (int r = 0; r < NREP; r++) {
      d[r] = deg_r[r * N_NODES + i];
      tot += d[r];
    }
  }
  s[t] = tot;
  __syncthreads();
#pragma unroll
  for (int off = 1; off < 256; off <<= 1) {
    int v = (t >= off) ? s[t - off] : 0;
    __syncthreads();
    s[t] += v;
    __syncthreads();
  }
  if (i < N_NODES) {
    int pre = blocksum[blockIdx.x] + s[t] - tot;  // exclusive prefix
    rowptr[i] = pre;
    int run = pre;
#pragma unroll
    for (int r = 0; r < NREP; r++) {
      coff[r * N_NODES + i] = run;
      run += d[r];
    }
    if (i == N_NODES - 1) rowptr[N_NODES] = N_EDGES;
  }
}

// 2 row-range passes keep the csr write region (~3.2 MB) L2-resident.
// Cursor atomics hit only replica blockIdx&7 -> no cross-XCD bouncing.
__global__ __launch_bounds__(256) void scatter_kernel(
    const int* __restrict__ erow, const unsigned* __restrict__ pval,
    int* __restrict__ coff, unsigned* __restrict__ csr, int rowLo, int rowHi) {
  unsigned e = blockIdx.x * 256 + threadIdx.x;
  int r = erow[e];
  if (r < rowLo || r >= rowHi) return;
  int p = atomicAdd(&coff[(blockIdx.x & (NREP - 1)) * N_NODES + r], 1);
  csr[p] = pval[e];
}

// ---------------------------------------------------------------------------
// W1T[n][k] = bf16(W1[k][n])  (128 x 512 bf16)
// ---------------------------------------------------------------------------
__global__ __launch_bounds__(256) void w1t_kernel(
    const float* __restrict__ W1, unsigned short* __restrict__ W1T) {
  int id = blockIdx.x * 256 + threadIdx.x;  // 65536 exact
  int n = id & 127, k = id >> 7;
  W1T[n * NFEAT + k] = f2bu(W1[k * HIDDEN + n]);
}

// ---------------------------------------------------------------------------
// GEMM1 (MFMA bf16): support = bf16(x) @ bf16(W1), fp32 acc. (r4-verified)
// ---------------------------------------------------------------------------
__global__ __launch_bounds__(256) void gemm1_mfma(
    const float* __restrict__ x, const unsigned short* __restrict__ W1T,
    unsigned short* __restrict__ support) {
  __shared__ short8 As[512];  // chunk = q*128 + row
  __shared__ short8 Bs[512];  // chunk = q*128 + col
  const int t = threadIdx.x;
  const int lane = t & 63;
  const int w = t >> 6;
  const int quad = lane >> 4;
  const int l15 = lane & 15;
  const int node_base = blockIdx.x * 128;
  const int mbase = (w >> 1) * 64;
  const int nbase = (w & 1) * 64;

  f32x4 acc[4][4] = {};

  for (int k0 = 0; k0 < NFEAT; k0 += 32) {
#pragma unroll
    for (int i = 0; i < 2; i++) {
      int lin = i * 256 + t;        // 0..511
      int n = lin >> 2, q = lin & 3;
      int row = node_base + n;
      if (row >= N_NODES) row = N_NODES - 1;
      const float* src = &x[(size_t)row * NFEAT + k0 + q * 8];
      float4 a = *(const float4*)src;
      float4 b = *(const float4*)(src + 4);
      short8 p;
      p[0] = (short)f2bu(a.x); p[1] = (short)f2bu(a.y);
      p[2] = (short)f2bu(a.z); p[3] = (short)f2bu(a.w);
      p[4] = (short)f2bu(b.x); p[5] = (short)f2bu(b.y);
      p[6] = (short)f2bu(b.z); p[7] = (short)f2bu(b.w);
      As[q * 128 + n] = p;
      Bs[q * 128 + n] = *(const short8*)&W1T[(size_t)n * NFEAT + k0 + q * 8];
    }
    __syncthreads();
    short8 af[4], bfr[4];
#pragma unroll
    for (int mt = 0; mt < 4; mt++)
      af[mt] = As[quad * 128 + mbase + mt * 16 + l15];
#pragma unroll
    for (int nt = 0; nt < 4; nt++)
      bfr[nt] = Bs[quad * 128 + nbase + nt * 16 + l15];
#pragma unroll
    for (int mt = 0; mt < 4; mt++)
#pragma unroll
      for (int nt = 0; nt < 4; nt++)
        acc[mt][nt] = __builtin_amdgcn_mfma_f32_16x16x32_bf16(
            af[mt], bfr[nt], acc[mt][nt], 0, 0, 0);
    __syncthreads();
  }

#pragma unroll
  for (int mt = 0; mt < 4; mt++)
#pragma unroll
    for (int nt = 0; nt < 4; nt++)
#pragma unroll
      for (int r = 0; r < 4; r++) {
        int row = node_base + mbase + mt * 16 + quad * 4 + r;
        int col = nbase + nt * 16 + l15;
        if (row < N_NODES)
          support[(size_t)row * HIDDEN + col] = f2bu(acc[mt][nt][r]);
      }
}

// ---------------------------------------------------------------------------
// SpMM1 fused: wave per row, 4-edge unroll. csr packed 4B.
// h[row] = bf16(dropout(relu(sum val*support[col] + b1)))
// ---------------------------------------------------------------------------
__global__ __launch_bounds__(256) void spmm1_fused(
    const unsigned* __restrict__ csr, const int* __restrict__ rowptr,
    const unsigned* __restrict__ sup,  // support rows = 64 uints (bf162)
    const float* __restrict__ b1, unsigned* __restrict__ h) {
  const int row = blockIdx.x * 4 + (threadIdx.x >> 6);
  const int lane = threadIdx.x & 63;
  const int beg = rowptr[row], end = rowptr[row + 1];
  float ax = 0.f, ay = 0.f;
  int j = beg;
  for (; j + 3 < end; j += 4) {
    unsigned p0 = csr[j], p1 = csr[j + 1], p2 = csr[j + 2], p3 = csr[j + 3];
    unsigned u0 = sup[(p0 & 0xffffu) * 64 + lane];
    unsigned u1 = sup[(p1 & 0xffffu) * 64 + lane];
    unsigned u2 = sup[(p2 & 0xffffu) * 64 + lane];
    unsigned u3 = sup[(p3 & 0xffffu) * 64 + lane];
    float v0 = __uint_as_float(p0 & 0xffff0000u);
    float v1 = __uint_as_float(p1 & 0xffff0000u);
    float v2 = __uint_as_float(p2 & 0xffff0000u);
    float v3 = __uint_as_float(p3 & 0xffff0000u);
    ax += v0 * __uint_as_float(u0 << 16) + v1 * __uint_as_float(u1 << 16) +
          v2 * __uint_as_float(u2 << 16) + v3 * __uint_as_float(u3 << 16);
    ay += v0 * __uint_as_float(u0 & 0xffff0000u) +
          v1 * __uint_as_float(u1 & 0xffff0000u) +
          v2 * __uint_as_float(u2 & 0xffff0000u) +
          v3 * __uint_as_float(u3 & 0xffff0000u);
  }
  for (; j < end; j++) {
    unsigned p0 = csr[j];
    unsigned u0 = sup[(p0 & 0xffffu) * 64 + lane];
    float v0 = __uint_as_float(p0 & 0xffff0000u);
    ax += v0 * __uint_as_float(u0 << 16);
    ay += v0 * __uint_as_float(u0 & 0xffff0000u);
  }
  const unsigned i0 = (unsigned)row * HIDDEN + lane * 2;
  float vx = fmaxf(ax + b1[lane * 2], 0.f);
  float vy = fmaxf(ay + b1[lane * 2 + 1], 0.f);
  vx = (threefry_bits(i0) >> 31) ? 0.f : 2.f * vx;
  vy = (threefry_bits(i0 + 1) >> 31) ? 0.f : 2.f * vy;
  h[(unsigned)row * 64 + lane] = (unsigned)f2bu(vx) | ((unsigned)f2bu(vy) << 16);
}

// ---------------------------------------------------------------------------
// GEMM2: h2[50000,40] = h(bf16) @ W2, fp32 compute, bf16 out. (r4-verified)
// ---------------------------------------------------------------------------
__global__ __launch_bounds__(256) void gemm2_kernel(
    const uint4* __restrict__ h,  // rows = 16 uint4 (8 bf16 each)
    const float* __restrict__ W2, unsigned short* __restrict__ h2) {
  __shared__ float Hs[64][132];
  __shared__ float Ws[40][132];
  const int t = threadIdx.x;
  const int node_base = blockIdx.x * 64;
#pragma unroll
  for (int i = 0; i < 4; i++) {
    int lin = i * 256 + t;
    int nloc = lin >> 4, c8 = lin & 15;
    int n = node_base + nloc;
    if (n >= N_NODES) n = N_NODES - 1;
    uint4 u = h[(size_t)n * 16 + c8];
    float* d = &Hs[nloc][c8 * 8];
    d[0] = __uint_as_float(u.x << 16); d[1] = __uint_as_float(u.x & 0xffff0000u);
    d[2] = __uint_as_float(u.y << 16); d[3] = __uint_as_float(u.y & 0xffff0000u);
    d[4] = __uint_as_float(u.z << 16); d[5] = __uint_as_float(u.z & 0xffff0000u);
    d[6] = __uint_as_float(u.w << 16); d[7] = __uint_as_float(u.w & 0xffff0000u);
  }
#pragma unroll
  for (int i = 0; i < 20; i++) {
    int l = t + i * 256;
    int k = l / NCLASS, f = l % NCLASS;
    Ws[f][k] = W2[l];
  }
  __syncthreads();
  const int nloc = t >> 2;
  const int fb = t & 3;
  const int n = node_base + nloc;
  float acc[10];
#pragma unroll
  for (int j = 0; j < 10; j++) acc[j] = 0.f;
  for (int k = 0; k < HIDDEN; k += 4) {
    float4 a = *(const float4*)&Hs[nloc][k];
#pragma unroll
    for (int j = 0; j < 10; j++) {
      float4 wv = *(const float4*)&Ws[fb + 4 * j][k];
      acc[j] += a.x * wv.x + a.y * wv.y + a.z * wv.z + a.w * wv.w;
    }
  }
  if (n < N_NODES) {
#pragma unroll
    for (int j = 0; j < 10; j++)
      h2[(size_t)n * NCLASS + fb + 4 * j] = f2bu(acc[j]);
  }
}

// ---------------------------------------------------------------------------
// SpMM2 fused: wave per row, 4 edges in flight (half-split x 2-unroll).
// ---------------------------------------------------------------------------
__global__ __launch_bounds__(256) void spmm2_fused(
    const unsigned* __restrict__ csr, const int* __restrict__ rowptr,
    const unsigned* __restrict__ h2u,  // rows = 20 uints
    const float* __restrict__ b2, float* __restrict__ out) {
  const int row = blockIdx.x * 4 + (threadIdx.x >> 6);
  const int lane = threadIdx.x & 63;
  const int half = lane >> 5;
  const int il = lane & 31;
  const unsigned ilc = (il < 20) ? (unsigned)il : 19u;
  const int beg = rowptr[row], end = rowptr[row + 1];
  float ax = 0.f, ay = 0.f;
  int j = beg + half;
  for (; j + 2 < end; j += 4) {  // edges j and j+2 (this half's parity)
    unsigned p0 = csr[j], p1 = csr[j + 2];
    unsigned u0 = h2u[(p0 & 0xffffu) * 20 + ilc];
    unsigned u1 = h2u[(p1 & 0xffffu) * 20 + ilc];
    float v0 = __uint_as_float(p0 & 0xffff0000u);
    float v1 = __uint_as_float(p1 & 0xffff0000u);
    ax += v0 * __uint_as_float(u0 << 16) + v1 * __uint_as_float(u1 << 16);
    ay += v0 * __uint_as_float(u0 & 0xffff0000u) +
          v1 * __uint_as_float(u1 & 0xffff0000u);
  }
  for (; j < end; j += 2) {
    unsigned p0 = csr[j];
    unsigned u0 = h2u[(p0 & 0xffffu) * 20 + ilc];
    float v0 = __uint_as_float(p0 & 0xffff0000u);
    ax += v0 * __uint_as_float(u0 << 16);
    ay += v0 * __uint_as_float(u0 & 0xffff0000u);
  }
  ax += __shfl_xor(ax, 32);
  ay += __shfl_xor(ay, 32);
  if (half == 0 && il < 20) {
    float2 r;
    r.x = fmaxf(ax + b2[il * 2], 0.f);
    r.y = fmaxf(ay + b2[il * 2 + 1], 0.f);
    *(float2*)&out[(unsigned)row * NCLASS + il * 2] = r;
  }
}

extern "C" void kernel_launch(void* const* d_in, const int* in_sizes, int n_in,
                              void* d_out, int out_size, void* d_ws,
                              size_t ws_size, hipStream_t stream) {
  const float* x     = (const float*)d_in[0];
  const int*   erow  = (const int*)d_in[1];
  const int*   ecol  = (const int*)d_in[2];
  const float* evals = (const float*)d_in[3];
  const float* W1    = (const float*)d_in[4];
  const float* b1    = (const float*)d_in[5];
  const float* W2    = (const float*)d_in[6];
  const float* b2    = (const float*)d_in[7];
  float* out = (float*)d_out;

  // ws layout (bytes): support 12.8M | h 12.8M | h2 4M | W1T 128K |
  // csr 6.4M | pval 6.4M | rowptr 200K | blocksum 1K | deg_r 1.6M |
  // coff 1.6M   (~46 MB)
  char* base = (char*)d_ws;
  unsigned short* support = (unsigned short*)base;
  unsigned short* h   = (unsigned short*)(base + 12800000);
  unsigned short* h2  = (unsigned short*)(base + 25600000);
  unsigned short* W1T = (unsigned short*)(base + 29600000);
  unsigned* csr  = (unsigned*)(base + 29731072);
  unsigned* pval = (unsigned*)(base + 29731072 + (size_t)N_EDGES * 4);
  int* rowptr   = (int*)(base + 29731072 + (size_t)N_EDGES * 8);
  int* blocksum = rowptr + (N_NODES + 1);
  int* deg_r    = blocksum + 256;
  int* coff     = deg_r + NREP * N_NODES;

  hipMemsetAsync(deg_r, 0, NREP * N_NODES * sizeof(int), stream);

  hist_pack_kernel<<<N_EDGES / 256, 256, 0, stream>>>(erow, ecol, evals,
                                                      deg_r, pval);
  partial_kernel<<<SCAN_BLOCKS, 256, 0, stream>>>(deg_r, blocksum);
  scanblk_kernel<<<1, 256, 0, stream>>>(blocksum);
  final_kernel<<<SCAN_BLOCKS, 256, 0, stream>>>(deg_r, blocksum, rowptr, coff);
  // 2 row-range passes: each pass's csr write region (~3.2 MB) fits per-XCD L2
  scatter_kernel<<<N_EDGES / 256, 256, 0, stream>>>(erow, pval, coff, csr,
                                                    0, 25000);
  scatter_kernel<<<N_EDGES / 256, 256, 0, stream>>>(erow, pval, coff, csr,
                                                    25000, 50000);

  w1t_kernel<<<256, 256, 0, stream>>>(W1, W1T);
  gemm1_mfma<<<(N_NODES + 127) / 128, 256, 0, stream>>>(x, W1T, support);
  spmm1_fused<<<N_NODES / 4, 256, 0, stream>>>(csr, rowptr,
                                               (const unsigned*)support, b1,
                                               (unsigned*)h);
  gemm2_kernel<<<(N_NODES + 63) / 64, 256, 0, stream>>>((const uint4*)h, W2, h2);
  spmm2_fused<<<N_NODES / 4, 256, 0, stream>>>(csr, rowptr,
                                               (const unsigned*)h2, b2, out);
}